// Round 1
// baseline (414.632 us; speedup 1.0000x reference)
//
#include <hip/hip_runtime.h>
#include <stdint.h>

// ---------- types / helpers ----------
typedef __attribute__((ext_vector_type(8))) __bf16 bf16x8;   // MFMA A/B operand (4 VGPR)
typedef __attribute__((ext_vector_type(4))) float  f32x4;    // MFMA C/D operand

#define MFMA16(A, B, C) __builtin_amdgcn_mfma_f32_16x16x32_bf16((A), (B), (C), 0, 0, 0)

__device__ __forceinline__ unsigned short f2b(float f) {   // f32 -> bf16 RNE
  union { float f; uint32_t u; } c; c.f = f;
  uint32_t u = c.u;
  u += 0x7fffu + ((u >> 16) & 1u);
  return (unsigned short)(u >> 16);
}
__device__ __forceinline__ float b2f(unsigned short s) {
  union { uint32_t u; float f; } c; c.u = ((uint32_t)s) << 16;
  return c.f;
}
__device__ __forceinline__ void async_cp16(const void* g, void* l) {
  __builtin_amdgcn_global_load_lds((const __attribute__((address_space(1))) uint32_t*)g,
                                   (__attribute__((address_space(3))) uint32_t*)l, 16, 0, 0);
}

// ---------- elementwise: x -> hi/lo bf16 ----------
__global__ __launch_bounds__(256) void split_hi_lo(const float* __restrict__ in,
                                                   unsigned short* __restrict__ hi,
                                                   unsigned short* __restrict__ lo, int n4) {
  int i = blockIdx.x * 256 + threadIdx.x;
  if (i >= n4) return;
  const float4 v = ((const float4*)in)[i];
  float f[4] = {v.x, v.y, v.z, v.w};
  unsigned short hs[4], ls[4];
#pragma unroll
  for (int j = 0; j < 4; ++j) {
    hs[j] = f2b(f[j]);
    ls[j] = f2b(f[j] - b2f(hs[j]));
  }
  ((ushort4*)hi)[i] = make_ushort4(hs[0], hs[1], hs[2], hs[3]);
  ((ushort4*)lo)[i] = make_ushort4(ls[0], ls[1], ls[2], ls[3]);
}

// ---------- transpose + split: src[rows][cols] f32 -> dst[cols][rows] bf16 (hi, optional lo) ----------
template <int WLO>
__global__ __launch_bounds__(256) void transpose_split(const float* __restrict__ src,
                                                       unsigned short* __restrict__ dh,
                                                       unsigned short* __restrict__ dl,
                                                       int rows, int cols) {
  __shared__ float tile[64][65];
  const int r0 = blockIdx.y * 64, c0 = blockIdx.x * 64;
  const int t = threadIdx.x;
#pragma unroll
  for (int i = 0; i < 4; ++i) {
    int c = i * 256 + t;
    int rr = c >> 4, cc = (c & 15) << 2;
    const float4 v = *(const float4*)(src + (size_t)(r0 + rr) * cols + c0 + cc);
    tile[rr][cc] = v.x; tile[rr][cc + 1] = v.y; tile[rr][cc + 2] = v.z; tile[rr][cc + 3] = v.w;
  }
  __syncthreads();
#pragma unroll
  for (int i = 0; i < 4; ++i) {
    int c = i * 256 + t;
    int rr = c >> 4, cc = (c & 15) << 2;  // rr: out row (src col), cc: out col (src row)
    unsigned short hs[4], ls[4];
#pragma unroll
    for (int j = 0; j < 4; ++j) {
      float v = tile[cc + j][rr];
      hs[j] = f2b(v);
      ls[j] = f2b(v - b2f(hs[j]));
    }
    *(ushort4*)(dh + (size_t)(c0 + rr) * rows + r0 + cc) = make_ushort4(hs[0], hs[1], hs[2], hs[3]);
    if (WLO)
      *(ushort4*)(dl + (size_t)(c0 + rr) * rows + r0 + cc) = make_ushort4(ls[0], ls[1], ls[2], ls[3]);
  }
}

// ---------- 128x128-tile MFMA GEMM, K=2048, A[M][K], B[N][K] (pre-transposed) ----------
// NTERMS: 1 = Ah@Bh ; 3 = Ah@Bh + Al@Bh + Ah@Bl (near-f32 via bf16 split)
// EPI: 0 = f32 C[row*2048+col] + bias
//      1 = QK split write: col<2048 -> (o0,o1)=Q hi/lo, else (o2,o3)=K hi/lo, col-2048
//      2 = V^T write: o0[(col)*2048 + row..row+3] bf16 (col = h*128+d)
template <int NTERMS, int EPI>
__global__ __launch_bounds__(256, 2) void gemm_bf16(
    const unsigned short* __restrict__ Ah, const unsigned short* __restrict__ Al,
    const unsigned short* __restrict__ Bh, const unsigned short* __restrict__ Bl,
    const float* __restrict__ bias,
    void* __restrict__ o0, void* __restrict__ o1, void* __restrict__ o2, void* __restrict__ o3) {
  constexpr int K = 2048;
  __shared__ unsigned short sA[(NTERMS > 1) ? 2 : 1][128 * 32];
  __shared__ unsigned short sB[(NTERMS > 1) ? 2 : 1][128 * 32];
  const int tid = threadIdx.x;
  const int wave = tid >> 6, lane = tid & 63;
  const int l16 = lane & 15, lq = lane >> 4;
  const int wr = wave >> 1, wc = wave & 1;
  const int m0 = blockIdx.y * 128, n0 = blockIdx.x * 128;

  f32x4 acc[4][4] = {};

  for (int k0 = 0; k0 < K; k0 += 32) {
    // stage tiles (chunk-XOR swizzle: LDS slot (row,cc) holds global chunk (row, cc^(row&3)))
#pragma unroll
    for (int i = 0; i < 2; ++i) {
      int c = i * 256 + tid;               // 512 chunks of 8 bf16 per tile
      int row = c >> 2, cc = c & 3;
      int gcol = ((cc ^ (row & 3)) << 3);
      size_t ga = (size_t)(m0 + row) * K + k0 + gcol;
      size_t gb = (size_t)(n0 + row) * K + k0 + gcol;
      async_cp16(Ah + ga, sA[0] + c * 8);
      async_cp16(Bh + gb, sB[0] + c * 8);
      if (NTERMS > 1) {
        async_cp16(Al + ga, sA[1] + c * 8);
        async_cp16(Bl + gb, sB[1] + c * 8);
      }
    }
    __syncthreads();

    bf16x8 ah[4], al[4], bh[4], bl[4];
#pragma unroll
    for (int mi = 0; mi < 4; ++mi) {
      int row = wr * 64 + mi * 16 + l16;
      int off = row * 32 + ((lq ^ (row & 3)) << 3);
      ah[mi] = *(const bf16x8*)(sA[0] + off);
      if (NTERMS > 1) al[mi] = *(const bf16x8*)(sA[1] + off);
    }
#pragma unroll
    for (int ni = 0; ni < 4; ++ni) {
      int row = wc * 64 + ni * 16 + l16;
      int off = row * 32 + ((lq ^ (row & 3)) << 3);
      bh[ni] = *(const bf16x8*)(sB[0] + off);
      if (NTERMS > 1) bl[ni] = *(const bf16x8*)(sB[1] + off);
    }
#pragma unroll
    for (int mi = 0; mi < 4; ++mi)
#pragma unroll
      for (int ni = 0; ni < 4; ++ni) {
        acc[mi][ni] = MFMA16(ah[mi], bh[ni], acc[mi][ni]);
        if (NTERMS > 1) {
          acc[mi][ni] = MFMA16(al[mi], bh[ni], acc[mi][ni]);
          acc[mi][ni] = MFMA16(ah[mi], bl[ni], acc[mi][ni]);
        }
      }
    __syncthreads();
  }

  // epilogue: C/D layout col=lane&15, row=(lane>>4)*4+reg (m89-verified)
#pragma unroll
  for (int mi = 0; mi < 4; ++mi) {
#pragma unroll
    for (int ni = 0; ni < 4; ++ni) {
      int row = m0 + wr * 64 + mi * 16 + lq * 4;
      int col = n0 + wc * 64 + ni * 16 + l16;
      float bv = bias[col];
      if (EPI == 0) {
        float* C = (float*)o0;
#pragma unroll
        for (int r = 0; r < 4; ++r)
          C[(size_t)(row + r) * 2048 + col] = acc[mi][ni][r] + bv;
      } else if (EPI == 1) {
        unsigned short* dh; unsigned short* dl; int cc;
        if (col < 2048) { dh = (unsigned short*)o0; dl = (unsigned short*)o1; cc = col; }
        else           { dh = (unsigned short*)o2; dl = (unsigned short*)o3; cc = col - 2048; }
#pragma unroll
        for (int r = 0; r < 4; ++r) {
          float v = acc[mi][ni][r] + bv;
          unsigned short h = f2b(v);
          unsigned short l = f2b(v - b2f(h));
          dh[(size_t)(row + r) * 2048 + cc] = h;
          dl[(size_t)(row + r) * 2048 + cc] = l;
        }
      } else {  // EPI == 2 : V^T [h*128+d][s] = col row-block; 4 consecutive s per lane
        unsigned short* vt = (unsigned short*)o0;
        unsigned short hs[4];
#pragma unroll
        for (int r = 0; r < 4; ++r) hs[r] = f2b(acc[mi][ni][r] + bv);
        *(ushort4*)(vt + (size_t)col * 2048 + row) = make_ushort4(hs[0], hs[1], hs[2], hs[3]);
      }
    }
  }
}

// ---------- flash attention (causal, no 1/sqrt(d) scaling — faithful to reference) ----------
// BQ=64 (4 waves x 16 rows), K-tiles of 64, d=128. Q/K hi-lo split-3 logits, bf16 PV.
__global__ __launch_bounds__(256, 2) void attn_fwd(
    const unsigned short* __restrict__ Qh, const unsigned short* __restrict__ Ql,
    const unsigned short* __restrict__ Kh, const unsigned short* __restrict__ Kl,
    const unsigned short* __restrict__ Vt, unsigned short* __restrict__ aout) {
  const int head = blockIdx.y;
  const int x = blockIdx.x;                       // 0..31
  const int qt = (x & 1) ? (31 - (x >> 1)) : (x >> 1);  // pair long/short causal blocks
  const int tid = threadIdx.x;
  const int wave = tid >> 6, lane = tid & 63;
  const int l16 = lane & 15, lq = lane >> 4;

  __shared__ unsigned short sKh[64 * 128];
  __shared__ unsigned short sKl[64 * 128];
  __shared__ unsigned short sV[128 * 64];         // [d][kseq]
  __shared__ unsigned short sP[4][16 * 72];       // per-wave P tile, padded stride 72

  const int q0 = qt * 64 + wave * 16;

  // hoist Q fragments (rows q0+l16, d chunks of 8)
  bf16x8 qh[4], ql[4];
#pragma unroll
  for (int kc = 0; kc < 4; ++kc) {
    size_t off = (size_t)(q0 + l16) * 2048 + head * 128 + kc * 32 + lq * 8;
    qh[kc] = *(const bf16x8*)(Qh + off);
    ql[kc] = *(const bf16x8*)(Ql + off);
  }

  f32x4 o[8] = {};
  float mst[4], lst[4];
#pragma unroll
  for (int r = 0; r < 4; ++r) { mst[r] = -1e30f; lst[r] = 0.f; }

  const int ktmax = qt + 1;
  for (int kt = 0; kt < ktmax; ++kt) {
    // stage K hi/lo [64][128] and V^T [128][64], 8-chunk XOR swizzle per row
#pragma unroll
    for (int i = 0; i < 4; ++i) {
      int c = i * 256 + tid;
      {
        int row = c >> 4, cc = c & 15;
        int gc = ((cc ^ (row & 7)) << 3);
        size_t g = (size_t)(kt * 64 + row) * 2048 + head * 128 + gc;
        async_cp16(Kh + g, sKh + c * 8);
        async_cp16(Kl + g, sKl + c * 8);
      }
      {
        int row = c >> 3, cc = c & 7;
        int gc = ((cc ^ (row & 7)) << 3);
        size_t g = (size_t)(head * 128 + row) * 2048 + kt * 64 + gc;
        async_cp16(Vt + g, sV + c * 8);
      }
    }
    __syncthreads();

    // QK^T: S[16 q][64 k], split-3
    f32x4 s[4] = {};
#pragma unroll
    for (int kc = 0; kc < 4; ++kc) {
#pragma unroll
      for (int nk = 0; nk < 4; ++nk) {
        int krow = nk * 16 + l16;
        int off = krow * 128 + ((((kc << 2) + lq) ^ (krow & 7)) << 3);
        bf16x8 kbh = *(const bf16x8*)(sKh + off);
        bf16x8 kbl = *(const bf16x8*)(sKl + off);
        s[nk] = MFMA16(qh[kc], kbh, s[nk]);
        s[nk] = MFMA16(ql[kc], kbh, s[nk]);
        s[nk] = MFMA16(qh[kc], kbl, s[nk]);
      }
    }

    // causal mask + online softmax (row = q0 + lq*4 + r; col = kt*64 + nk*16 + l16)
#pragma unroll
    for (int r = 0; r < 4; ++r) {
      const int qg = q0 + lq * 4 + r;
      float mx = -1e30f;
      float pv[4];
#pragma unroll
      for (int nk = 0; nk < 4; ++nk) {
        int kg = kt * 64 + nk * 16 + l16;
        float v = s[nk][r];
        if (kg > qg) v = -1e30f;
        pv[nk] = v;
        mx = fmaxf(mx, v);
      }
#pragma unroll
      for (int off = 1; off < 16; off <<= 1) mx = fmaxf(mx, __shfl_xor(mx, off));
      float mnew = fmaxf(mst[r], mx);
      float scale = __expf(mst[r] - mnew);
      float rsum = 0.f;
#pragma unroll
      for (int nk = 0; nk < 4; ++nk) {
        unsigned short pb = f2b(__expf(pv[nk] - mnew));
        sP[wave][(lq * 4 + r) * 72 + nk * 16 + l16] = pb;
        rsum += b2f(pb);  // denominator matches bf16-rounded numerator
      }
#pragma unroll
      for (int off = 1; off < 16; off <<= 1) rsum += __shfl_xor(rsum, off);
      lst[r] = lst[r] * scale + rsum;
      mst[r] = mnew;
#pragma unroll
      for (int nd = 0; nd < 8; ++nd) o[nd][r] *= scale;
    }

    // PV: O[16 q][128 d] += P[16][64] @ V[64][128]
#pragma unroll
    for (int kc2 = 0; kc2 < 2; ++kc2) {
      bf16x8 pa = *(const bf16x8*)(&sP[wave][l16 * 72 + kc2 * 32 + lq * 8]);
#pragma unroll
      for (int nd = 0; nd < 8; ++nd) {
        int vrow = nd * 16 + l16;
        int off = vrow * 64 + ((((kc2 << 2) + lq) ^ (vrow & 7)) << 3);
        bf16x8 vb = *(const bf16x8*)(sV + off);
        o[nd] = MFMA16(pa, vb, o[nd]);
      }
    }
    __syncthreads();
  }

#pragma unroll
  for (int r = 0; r < 4; ++r) lst[r] = 1.f / lst[r];
#pragma unroll
  for (int nd = 0; nd < 8; ++nd) {
#pragma unroll
    for (int r = 0; r < 4; ++r) {
      int sg = q0 + lq * 4 + r;
      aout[(size_t)sg * 2048 + head * 128 + nd * 16 + l16] = f2b(o[nd][r] * lst[r]);
    }
  }
}

// ---------- launch ----------
extern "C" void kernel_launch(void* const* d_in, const int* in_sizes, int n_in,
                              void* d_out, int out_size, void* d_ws, size_t ws_size,
                              hipStream_t stream) {
  const float* x    = (const float*)d_in[0];
  const float* Wqkv = (const float*)d_in[1];
  const float* bqkv = (const float*)d_in[2];
  const float* Wout = (const float*)d_in[3];
  const float* bout = (const float*)d_in[4];
  float* out = (float*)d_out;

  unsigned short* w = (unsigned short*)d_ws;
  const size_t SZ = (size_t)2048 * 2048;
  unsigned short* xh  = w;  w += SZ;
  unsigned short* xl  = w;  w += SZ;
  unsigned short* wqh = w;  w += (size_t)6144 * 2048;
  unsigned short* wql = w;  w += (size_t)6144 * 2048;
  unsigned short* wo  = w;  w += SZ;
  unsigned short* qh  = w;  w += SZ;
  unsigned short* ql  = w;  w += SZ;
  unsigned short* kh  = w;  w += SZ;
  unsigned short* kl  = w;  w += SZ;
  unsigned short* vt  = w;  w += SZ;
  unsigned short* ao  = w;  w += SZ;
  (void)ws_size; (void)in_sizes; (void)n_in; (void)out_size;

  split_hi_lo<<<4096, 256, 0, stream>>>(x, xh, xl, (int)(SZ / 4));
  transpose_split<1><<<dim3(96, 32), 256, 0, stream>>>(Wqkv, wqh, wql, 2048, 6144);
  transpose_split<0><<<dim3(32, 32), 256, 0, stream>>>(Wout, wo, nullptr, 2048, 2048);
  // QKV projection: Q,K columns with split-3 precision; V columns plain bf16 into V^T layout
  gemm_bf16<3, 1><<<dim3(32, 16), 256, 0, stream>>>(xh, xl, wqh, wql, bqkv, qh, ql, kh, kl);
  gemm_bf16<1, 2><<<dim3(16, 16), 256, 0, stream>>>(xh, nullptr, wqh + (size_t)4096 * 2048, nullptr,
                                                    bqkv + 4096, vt, nullptr, nullptr, nullptr);
  attn_fwd<<<dim3(32, 16), 256, 0, stream>>>(qh, ql, kh, kl, vt, ao);
  gemm_bf16<1, 0><<<dim3(16, 16), 256, 0, stream>>>(ao, nullptr, wo, nullptr, bout, out,
                                                    nullptr, nullptr, nullptr);
}

// Round 4
// 381.755 us; speedup vs baseline: 1.0861x; 1.0861x over previous
//
#include <hip/hip_runtime.h>
#include <stdint.h>

// ---------- types / helpers ----------
typedef __attribute__((ext_vector_type(8))) __bf16 bf16x8;   // MFMA A/B operand (4 VGPR)
typedef __attribute__((ext_vector_type(4))) float  f32x4;    // MFMA C/D operand

#define MFMA16(A, B, C) __builtin_amdgcn_mfma_f32_16x16x32_bf16((A), (B), (C), 0, 0, 0)

__device__ __forceinline__ unsigned short f2b(float f) {   // f32 -> bf16 RNE
  union { float f; uint32_t u; } c; c.f = f;
  uint32_t u = c.u;
  u += 0x7fffu + ((u >> 16) & 1u);
  return (unsigned short)(u >> 16);
}
__device__ __forceinline__ float b2f(unsigned short s) {
  union { uint32_t u; float f; } c; c.u = ((uint32_t)s) << 16;
  return c.f;
}
__device__ __forceinline__ void async_cp16(const void* g, void* l) {
  __builtin_amdgcn_global_load_lds((const __attribute__((address_space(1))) uint32_t*)g,
                                   (__attribute__((address_space(3))) uint32_t*)l, 16, 0, 0);
}

// ---------- elementwise: x -> hi/lo bf16 ----------
__global__ __launch_bounds__(256) void split_hi_lo(const float* __restrict__ in,
                                                   unsigned short* __restrict__ hi,
                                                   unsigned short* __restrict__ lo, int n4) {
  int i = blockIdx.x * 256 + threadIdx.x;
  if (i >= n4) return;
  const float4 v = ((const float4*)in)[i];
  float f[4] = {v.x, v.y, v.z, v.w};
  unsigned short hs[4], ls[4];
#pragma unroll
  for (int j = 0; j < 4; ++j) {
    hs[j] = f2b(f[j]);
    ls[j] = f2b(f[j] - b2f(hs[j]));
  }
  ((ushort4*)hi)[i] = make_ushort4(hs[0], hs[1], hs[2], hs[3]);
  ((ushort4*)lo)[i] = make_ushort4(ls[0], ls[1], ls[2], ls[3]);
}

// ---------- transpose + split: src[rows][cols] f32 -> dst[cols][rows] bf16 (hi, optional lo) ----------
template <int WLO>
__global__ __launch_bounds__(256) void transpose_split(const float* __restrict__ src,
                                                       unsigned short* __restrict__ dh,
                                                       unsigned short* __restrict__ dl,
                                                       int rows, int cols) {
  __shared__ float tile[64][65];
  const int r0 = blockIdx.y * 64, c0 = blockIdx.x * 64;
  const int t = threadIdx.x;
#pragma unroll
  for (int i = 0; i < 4; ++i) {
    int c = i * 256 + t;
    int rr = c >> 4, cc = (c & 15) << 2;
    const float4 v = *(const float4*)(src + (size_t)(r0 + rr) * cols + c0 + cc);
    tile[rr][cc] = v.x; tile[rr][cc + 1] = v.y; tile[rr][cc + 2] = v.z; tile[rr][cc + 3] = v.w;
  }
  __syncthreads();
#pragma unroll
  for (int i = 0; i < 4; ++i) {
    int c = i * 256 + t;
    int rr = c >> 4, cc = (c & 15) << 2;  // rr: out row (src col), cc: out col (src row)
    unsigned short hs[4], ls[4];
#pragma unroll
    for (int j = 0; j < 4; ++j) {
      float v = tile[cc + j][rr];
      hs[j] = f2b(v);
      ls[j] = f2b(v - b2f(hs[j]));
    }
    *(ushort4*)(dh + (size_t)(c0 + rr) * rows + r0 + cc) = make_ushort4(hs[0], hs[1], hs[2], hs[3]);
    if (WLO)
      *(ushort4*)(dl + (size_t)(c0 + rr) * rows + r0 + cc) = make_ushort4(ls[0], ls[1], ls[2], ls[3]);
  }
}

// ---------- 128x128-tile MFMA GEMM, K=2048, A[M][K], B[N][K] (pre-transposed) ----------
// NTERMS: 1 = Ah@Bh ; 3 = Ah@Bh + Al@Bh + Ah@Bl (near-f32 via bf16 split)
// EPI: 0 = f32 C[row*2048+col] + bias
//      1 = QK split write: col<2048 -> (o0,o1)=Q hi/lo, else (o2,o3)=K hi/lo, col-2048
//      2 = V^T write: o0[(col)*2048 + row..row+3] bf16 (col = h*128+d)
template <int NTERMS, int EPI>
__global__ __launch_bounds__(256, 2) void gemm_bf16(
    const unsigned short* __restrict__ Ah, const unsigned short* __restrict__ Al,
    const unsigned short* __restrict__ Bh, const unsigned short* __restrict__ Bl,
    const float* __restrict__ bias,
    void* __restrict__ o0, void* __restrict__ o1, void* __restrict__ o2, void* __restrict__ o3) {
  constexpr int K = 2048;
  __shared__ unsigned short sA[(NTERMS > 1) ? 2 : 1][128 * 32];
  __shared__ unsigned short sB[(NTERMS > 1) ? 2 : 1][128 * 32];
  const int tid = threadIdx.x;
  const int wave = tid >> 6, lane = tid & 63;
  const int l16 = lane & 15, lq = lane >> 4;
  const int wr = wave >> 1, wc = wave & 1;
  const int m0 = blockIdx.y * 128, n0 = blockIdx.x * 128;

  f32x4 acc[4][4] = {};

  for (int k0 = 0; k0 < K; k0 += 32) {
    // stage tiles (chunk-XOR swizzle: LDS slot (row,cc) holds global chunk (row, cc^(row&3)))
#pragma unroll
    for (int i = 0; i < 2; ++i) {
      int c = i * 256 + tid;               // 512 chunks of 8 bf16 per tile
      int row = c >> 2, cc = c & 3;
      int gcol = ((cc ^ (row & 3)) << 3);
      size_t ga = (size_t)(m0 + row) * K + k0 + gcol;
      size_t gb = (size_t)(n0 + row) * K + k0 + gcol;
      async_cp16(Ah + ga, sA[0] + c * 8);
      async_cp16(Bh + gb, sB[0] + c * 8);
      if (NTERMS > 1) {
        async_cp16(Al + ga, sA[1] + c * 8);
        async_cp16(Bl + gb, sB[1] + c * 8);
      }
    }
    __syncthreads();

    bf16x8 ah[4], al[4], bh[4], bl[4];
#pragma unroll
    for (int mi = 0; mi < 4; ++mi) {
      int row = wr * 64 + mi * 16 + l16;
      int off = row * 32 + ((lq ^ (row & 3)) << 3);
      ah[mi] = *(const bf16x8*)(sA[0] + off);
      if (NTERMS > 1) al[mi] = *(const bf16x8*)(sA[1] + off);
    }
#pragma unroll
    for (int ni = 0; ni < 4; ++ni) {
      int row = wc * 64 + ni * 16 + l16;
      int off = row * 32 + ((lq ^ (row & 3)) << 3);
      bh[ni] = *(const bf16x8*)(sB[0] + off);
      if (NTERMS > 1) bl[ni] = *(const bf16x8*)(sB[1] + off);
    }
#pragma unroll
    for (int mi = 0; mi < 4; ++mi)
#pragma unroll
      for (int ni = 0; ni < 4; ++ni) {
        acc[mi][ni] = MFMA16(ah[mi], bh[ni], acc[mi][ni]);
        if (NTERMS > 1) {
          acc[mi][ni] = MFMA16(al[mi], bh[ni], acc[mi][ni]);
          acc[mi][ni] = MFMA16(ah[mi], bl[ni], acc[mi][ni]);
        }
      }
    __syncthreads();
  }

  // epilogue: C/D layout col=lane&15, row=(lane>>4)*4+reg (m89-verified)
#pragma unroll
  for (int mi = 0; mi < 4; ++mi) {
#pragma unroll
    for (int ni = 0; ni < 4; ++ni) {
      int row = m0 + wr * 64 + mi * 16 + lq * 4;
      int col = n0 + wc * 64 + ni * 16 + l16;
      float bv = bias[col];
      if (EPI == 0) {
        float* C = (float*)o0;
#pragma unroll
        for (int r = 0; r < 4; ++r)
          C[(size_t)(row + r) * 2048 + col] = acc[mi][ni][r] + bv;
      } else if (EPI == 1) {
        unsigned short* dh; unsigned short* dl; int cc;
        if (col < 2048) { dh = (unsigned short*)o0; dl = (unsigned short*)o1; cc = col; }
        else           { dh = (unsigned short*)o2; dl = (unsigned short*)o3; cc = col - 2048; }
#pragma unroll
        for (int r = 0; r < 4; ++r) {
          float v = acc[mi][ni][r] + bv;
          unsigned short h = f2b(v);
          unsigned short l = f2b(v - b2f(h));
          dh[(size_t)(row + r) * 2048 + cc] = h;
          dl[(size_t)(row + r) * 2048 + cc] = l;
        }
      } else {  // EPI == 2 : V^T [h*128+d][s] = col row-block; 4 consecutive s per lane
        unsigned short* vt = (unsigned short*)o0;
        unsigned short hs[4];
#pragma unroll
        for (int r = 0; r < 4; ++r) hs[r] = f2b(acc[mi][ni][r] + bv);
        *(ushort4*)(vt + (size_t)col * 2048 + row) = make_ushort4(hs[0], hs[1], hs[2], hs[3]);
      }
    }
  }
}

// ---------- flash attention (causal, no 1/sqrt(d) scaling — faithful to reference) ----------
// BQ=64 (4 waves x 16 rows), K-tiles of 64, d=128.
// Swapped-operand scheme: S^T = MFMA(K,Q) so each lane's 16 scores share ONE q-row (q=lane&15)
// -> softmax = local ops + 2 shfl_xor; O^T = MFMA(V,P) so rescale is lane-uniform.
__global__ __launch_bounds__(256, 2) void attn_fwd(
    const unsigned short* __restrict__ Qh, const unsigned short* __restrict__ Ql,
    const unsigned short* __restrict__ Kh, const unsigned short* __restrict__ Kl,
    const unsigned short* __restrict__ Vt, unsigned short* __restrict__ aout) {
  const int head = blockIdx.y;
  const int x = blockIdx.x;                       // 0..31
  // balance CUs: co-resident blocks (b, b+256) differ only in head by 8 -> opposite qt length
  const int qt = (head < 8) ? x : (31 - x);
  const int tid = threadIdx.x;
  const int wave = tid >> 6, lane = tid & 63;
  const int l16 = lane & 15, lq = lane >> 4;

  __shared__ unsigned short sKh[64 * 128];
  __shared__ unsigned short sKl[64 * 128];
  __shared__ unsigned short sV[128 * 64];         // [d][kseq]
  __shared__ unsigned short sP[4][16 * 72];       // per-wave P tile [q][k], stride 72

  const int q0 = qt * 64 + wave * 16;

  // hoist Q fragments (rows q0+l16, d chunks of 8) — used as MFMA B-operand
  bf16x8 qh[4], ql[4];
#pragma unroll
  for (int kc = 0; kc < 4; ++kc) {
    size_t off = (size_t)(q0 + l16) * 2048 + head * 128 + kc * 32 + lq * 8;
    qh[kc] = *(const bf16x8*)(Qh + off);
    ql[kc] = *(const bf16x8*)(Ql + off);
  }

  f32x4 o[8] = {};                 // O^T: [d = nd*16 + lq*4 + r][q = l16]
  float mst = -1e30f, lst = 0.f;   // online-softmax state for q = l16 (replicated over lq)

  const int ktmax = qt + 1;
  for (int kt = 0; kt < ktmax; ++kt) {
    // stage K hi/lo [64][128] and V^T [128][64], 8-chunk XOR swizzle per row
#pragma unroll
    for (int i = 0; i < 4; ++i) {
      int c = i * 256 + tid;
      {
        int row = c >> 4, cc = c & 15;
        int gc = ((cc ^ (row & 7)) << 3);
        size_t g = (size_t)(kt * 64 + row) * 2048 + head * 128 + gc;
        async_cp16(Kh + g, sKh + c * 8);
        async_cp16(Kl + g, sKl + c * 8);
      }
      {
        int row = c >> 3, cc = c & 7;
        int gc = ((cc ^ (row & 7)) << 3);
        size_t g = (size_t)(head * 128 + row) * 2048 + kt * 64 + gc;
        async_cp16(Vt + g, sV + c * 8);
      }
    }
    __syncthreads();

    // S^T[64 k][16 q] in 4 reg-tiles: s[nk] rows k = kt*64 + nk*16 + lq*4 + r, col q = l16
    f32x4 s[4] = {};
#pragma unroll
    for (int kc = 0; kc < 4; ++kc) {
#pragma unroll
      for (int nk = 0; nk < 4; ++nk) {
        int krow = nk * 16 + l16;
        int off = krow * 128 + ((((kc << 2) + lq) ^ (krow & 7)) << 3);
        bf16x8 kbh = *(const bf16x8*)(sKh + off);
        bf16x8 kbl = *(const bf16x8*)(sKl + off);
        s[nk] = MFMA16(kbh, qh[kc], s[nk]);   // Kh·Qh^T
        s[nk] = MFMA16(kbh, ql[kc], s[nk]);   // Kh·Ql^T
        s[nk] = MFMA16(kbl, qh[kc], s[nk]);   // Kl·Qh^T
      }
    }

    // causal mask + online softmax — all 16 scores in this lane belong to q = q0 + l16
    const int qg = q0 + l16;
    float pv[16];
    float mx = -1e30f;
#pragma unroll
    for (int nk = 0; nk < 4; ++nk)
#pragma unroll
      for (int r = 0; r < 4; ++r) {
        int kg = kt * 64 + nk * 16 + lq * 4 + r;
        float v = s[nk][r];
        if (kg > qg) v = -1e30f;
        pv[nk * 4 + r] = v;
        mx = fmaxf(mx, v);
      }
    mx = fmaxf(mx, __shfl_xor(mx, 16));
    mx = fmaxf(mx, __shfl_xor(mx, 32));
    float mnew = fmaxf(mst, mx);
    float scale = __expf(mst - mnew);
    float rsum = 0.f;
#pragma unroll
    for (int nk = 0; nk < 4; ++nk) {
      unsigned short pb[4];
#pragma unroll
      for (int r = 0; r < 4; ++r) {
        pb[r] = f2b(__expf(pv[nk * 4 + r] - mnew));
        rsum += b2f(pb[r]);
      }
      // P[q = l16][k = nk*16 + lq*4 .. +3], aligned 8B write, wave-private
      *(ushort4*)(&sP[wave][l16 * 72 + nk * 16 + lq * 4]) = make_ushort4(pb[0], pb[1], pb[2], pb[3]);
    }
    rsum += __shfl_xor(rsum, 16);
    rsum += __shfl_xor(rsum, 32);
    lst = lst * scale + rsum;
    mst = mnew;
#pragma unroll
    for (int nd = 0; nd < 8; ++nd) {
      o[nd][0] *= scale; o[nd][1] *= scale; o[nd][2] *= scale; o[nd][3] *= scale;
    }

    // O^T += V^T·P^T : A = V^T d-rows (from sV), B = P q-rows (from sP)
#pragma unroll
    for (int kc2 = 0; kc2 < 2; ++kc2) {
      bf16x8 pb = *(const bf16x8*)(&sP[wave][l16 * 72 + kc2 * 32 + lq * 8]);
#pragma unroll
      for (int nd = 0; nd < 8; ++nd) {
        int vrow = nd * 16 + l16;
        int off = vrow * 64 + ((((kc2 << 2) + lq) ^ (vrow & 7)) << 3);
        bf16x8 vb = *(const bf16x8*)(sV + off);
        o[nd] = MFMA16(vb, pb, o[nd]);
      }
    }
    __syncthreads();
  }

  const float norm = 1.f / lst;
#pragma unroll
  for (int nd = 0; nd < 8; ++nd) {
    unsigned short hs[4];
#pragma unroll
    for (int r = 0; r < 4; ++r) hs[r] = f2b(o[nd][r] * norm);
    *(ushort4*)(aout + (size_t)(q0 + l16) * 2048 + head * 128 + nd * 16 + lq * 4) =
        make_ushort4(hs[0], hs[1], hs[2], hs[3]);
  }
}

// ---------- launch ----------
extern "C" void kernel_launch(void* const* d_in, const int* in_sizes, int n_in,
                              void* d_out, int out_size, void* d_ws, size_t ws_size,
                              hipStream_t stream) {
  const float* x    = (const float*)d_in[0];
  const float* Wqkv = (const float*)d_in[1];
  const float* bqkv = (const float*)d_in[2];
  const float* Wout = (const float*)d_in[3];
  const float* bout = (const float*)d_in[4];
  float* out = (float*)d_out;

  unsigned short* w = (unsigned short*)d_ws;
  const size_t SZ = (size_t)2048 * 2048;
  unsigned short* xh  = w;  w += SZ;
  unsigned short* xl  = w;  w += SZ;
  unsigned short* wqh = w;  w += (size_t)6144 * 2048;
  unsigned short* wql = w;  w += (size_t)6144 * 2048;
  unsigned short* wo  = w;  w += SZ;
  unsigned short* qh  = w;  w += SZ;
  unsigned short* ql  = w;  w += SZ;
  unsigned short* kh  = w;  w += SZ;
  unsigned short* kl  = w;  w += SZ;
  unsigned short* vt  = w;  w += SZ;
  unsigned short* ao  = w;  w += SZ;
  (void)ws_size; (void)in_sizes; (void)n_in; (void)out_size;

  split_hi_lo<<<4096, 256, 0, stream>>>(x, xh, xl, (int)(SZ / 4));
  transpose_split<1><<<dim3(96, 32), 256, 0, stream>>>(Wqkv, wqh, wql, 2048, 6144);
  transpose_split<0><<<dim3(32, 32), 256, 0, stream>>>(Wout, wo, nullptr, 2048, 2048);
  // QKV projection: Q,K columns with split-3 precision; V columns plain bf16 into V^T layout
  gemm_bf16<3, 1><<<dim3(32, 16), 256, 0, stream>>>(xh, xl, wqh, wql, bqkv, qh, ql, kh, kl);
  gemm_bf16<1, 2><<<dim3(16, 16), 256, 0, stream>>>(xh, nullptr, wqh + (size_t)4096 * 2048, nullptr,
                                                    bqkv + 4096, vt, nullptr, nullptr, nullptr);
  attn_fwd<<<dim3(32, 16), 256, 0, stream>>>(qh, ql, kh, kl, vt, ao);
  gemm_bf16<1, 0><<<dim3(16, 16), 256, 0, stream>>>(ao, nullptr, wo, nullptr, bout, out,
                                                    nullptr, nullptr, nullptr);
}

// Round 7
// 356.234 us; speedup vs baseline: 1.1639x; 1.0716x over previous
//
#include <hip/hip_runtime.h>
#include <stdint.h>

// ---------- types / helpers ----------
typedef __attribute__((ext_vector_type(8))) __bf16 bf16x8;   // MFMA A/B operand (4 VGPR)
typedef __attribute__((ext_vector_type(4))) float  f32x4;    // MFMA C/D operand

#define MFMA16(A, B, C) __builtin_amdgcn_mfma_f32_16x16x32_bf16((A), (B), (C), 0, 0, 0)

__device__ __forceinline__ unsigned short f2b(float f) {   // f32 -> bf16 RNE
  union { float f; uint32_t u; } c; c.f = f;
  uint32_t u = c.u;
  u += 0x7fffu + ((u >> 16) & 1u);
  return (unsigned short)(u >> 16);
}
__device__ __forceinline__ float b2f(unsigned short s) {
  union { uint32_t u; float f; } c; c.u = ((uint32_t)s) << 16;
  return c.f;
}
__device__ __forceinline__ void async_cp16(const void* g, void* l) {
  __builtin_amdgcn_global_load_lds((const __attribute__((address_space(1))) uint32_t*)g,
                                   (__attribute__((address_space(3))) uint32_t*)l, 16, 0, 0);
}

// ---------- elementwise: x -> hi/lo bf16 ----------
__global__ __launch_bounds__(256) void split_hi_lo(const float* __restrict__ in,
                                                   unsigned short* __restrict__ hi,
                                                   unsigned short* __restrict__ lo, int n4) {
  int i = blockIdx.x * 256 + threadIdx.x;
  if (i >= n4) return;
  const float4 v = ((const float4*)in)[i];
  float f[4] = {v.x, v.y, v.z, v.w};
  unsigned short hs[4], ls[4];
#pragma unroll
  for (int j = 0; j < 4; ++j) {
    hs[j] = f2b(f[j]);
    ls[j] = f2b(f[j] - b2f(hs[j]));
  }
  ((ushort4*)hi)[i] = make_ushort4(hs[0], hs[1], hs[2], hs[3]);
  ((ushort4*)lo)[i] = make_ushort4(ls[0], ls[1], ls[2], ls[3]);
}

// ---------- transpose + split: src[rows][cols] f32 -> dst[cols][rows] bf16 (hi, optional lo) ----------
template <int WLO>
__global__ __launch_bounds__(256) void transpose_split(const float* __restrict__ src,
                                                       unsigned short* __restrict__ dh,
                                                       unsigned short* __restrict__ dl,
                                                       int rows, int cols) {
  __shared__ float tile[64][65];
  const int r0 = blockIdx.y * 64, c0 = blockIdx.x * 64;
  const int t = threadIdx.x;
#pragma unroll
  for (int i = 0; i < 4; ++i) {
    int c = i * 256 + t;
    int rr = c >> 4, cc = (c & 15) << 2;
    const float4 v = *(const float4*)(src + (size_t)(r0 + rr) * cols + c0 + cc);
    tile[rr][cc] = v.x; tile[rr][cc + 1] = v.y; tile[rr][cc + 2] = v.z; tile[rr][cc + 3] = v.w;
  }
  __syncthreads();
#pragma unroll
  for (int i = 0; i < 4; ++i) {
    int c = i * 256 + t;
    int rr = c >> 4, cc = (c & 15) << 2;  // rr: out row (src col), cc: out col (src row)
    unsigned short hs[4], ls[4];
#pragma unroll
    for (int j = 0; j < 4; ++j) {
      float v = tile[cc + j][rr];
      hs[j] = f2b(v);
      ls[j] = f2b(v - b2f(hs[j]));
    }
    *(ushort4*)(dh + (size_t)(c0 + rr) * rows + r0 + cc) = make_ushort4(hs[0], hs[1], hs[2], hs[3]);
    if (WLO)
      *(ushort4*)(dl + (size_t)(c0 + rr) * rows + r0 + cc) = make_ushort4(ls[0], ls[1], ls[2], ls[3]);
  }
}

// ---------- 128x128-tile MFMA GEMM, K=2048, A[M][K], B[N][K] (pre-transposed) ----------
// NW: waves/block (4 -> 2x2 wave grid, 8 -> 2x4)
// EPI 0: f32 C[row*2048+col] + bias, 1-term.
// EPI 1: fused QKV. Blocks with n0<4096 run split-3 (Ah@Bh+Al@Bh+Ah@Bl) and write Q/K hi/lo;
//        blocks with n0>=4096 run 1-term and write V^T (o4[(col-4096)*2048 + row], bf16).
// LDS swizzle: slot (row,cc) holds global chunk cc^((row>>1)&3)  [conflict-free: 2 lanes/bank-group]
template <int NW, int EPI>
__global__ __launch_bounds__(NW * 64, 2) void gemm_bf16(
    const unsigned short* __restrict__ Ah, const unsigned short* __restrict__ Al,
    const unsigned short* __restrict__ Bh, const unsigned short* __restrict__ Bl,
    const float* __restrict__ bias,
    void* __restrict__ o0, void* __restrict__ o1, void* __restrict__ o2, void* __restrict__ o3,
    void* __restrict__ o4) {
  constexpr int K = 2048;
  constexpr int NBUF = (EPI == 1) ? 2 : 1;
  constexpr int WN = (NW == 8) ? 4 : 2;   // waves along N
  constexpr int WM = NW / WN;             // 2
  constexpr int MI = (128 / WM) / 16;     // 4
  constexpr int NI = (128 / WN) / 16;     // 4 (NW=4) or 2 (NW=8)
  __shared__ unsigned short sA[NBUF][128 * 32];
  __shared__ unsigned short sB[NBUF][128 * 32];
  const int tid = threadIdx.x;
  const int wave = tid >> 6, lane = tid & 63;
  const int l16 = lane & 15, lq = lane >> 4;
  const int wr = wave / WN, wc = wave % WN;
  const int m0 = blockIdx.y * 128, n0 = blockIdx.x * 128;
  const bool three = (EPI == 1) && (n0 < 4096);   // block-uniform

  f32x4 acc[MI][NI] = {};

  for (int k0 = 0; k0 < K; k0 += 32) {
#pragma unroll
    for (int i = 0; i < 512 / (NW * 64); ++i) {
      int c = i * (NW * 64) + tid;         // 512 chunks of 8 bf16 per tile
      int row = c >> 2, cc = c & 3;
      int gcol = ((cc ^ ((row >> 1) & 3)) << 3);
      size_t ga = (size_t)(m0 + row) * K + k0 + gcol;
      size_t gb = (size_t)(n0 + row) * K + k0 + gcol;
      async_cp16(Ah + ga, sA[0] + c * 8);
      async_cp16(Bh + gb, sB[0] + c * 8);
      if constexpr (EPI == 1) {
        if (three) {
          async_cp16(Al + ga, sA[1] + c * 8);
          async_cp16(Bl + gb, sB[1] + c * 8);
        }
      }
    }
    __syncthreads();

    bf16x8 ah[MI], al[MI], bh[NI], bl[NI];
#pragma unroll
    for (int mi = 0; mi < MI; ++mi) {
      int row = wr * (MI * 16) + mi * 16 + l16;
      int off = row * 32 + ((lq ^ ((row >> 1) & 3)) << 3);
      ah[mi] = *(const bf16x8*)(sA[0] + off);
      if constexpr (EPI == 1) {
        if (three) al[mi] = *(const bf16x8*)(sA[1] + off);
      }
    }
#pragma unroll
    for (int ni = 0; ni < NI; ++ni) {
      int row = wc * (NI * 16) + ni * 16 + l16;
      int off = row * 32 + ((lq ^ ((row >> 1) & 3)) << 3);
      bh[ni] = *(const bf16x8*)(sB[0] + off);
      if constexpr (EPI == 1) {
        if (three) bl[ni] = *(const bf16x8*)(sB[1] + off);
      }
    }
#pragma unroll
    for (int mi = 0; mi < MI; ++mi)
#pragma unroll
      for (int ni = 0; ni < NI; ++ni) {
        acc[mi][ni] = MFMA16(ah[mi], bh[ni], acc[mi][ni]);
        if constexpr (EPI == 1) {
          if (three) {
            acc[mi][ni] = MFMA16(al[mi], bh[ni], acc[mi][ni]);
            acc[mi][ni] = MFMA16(ah[mi], bl[ni], acc[mi][ni]);
          }
        }
      }
    __syncthreads();
  }

  // epilogue: C/D layout col=lane&15, row=(lane>>4)*4+reg (m89-verified)
#pragma unroll
  for (int mi = 0; mi < MI; ++mi) {
#pragma unroll
    for (int ni = 0; ni < NI; ++ni) {
      int row = m0 + wr * (MI * 16) + mi * 16 + lq * 4;
      int col = n0 + wc * (NI * 16) + ni * 16 + l16;
      float bv = bias[col];
      if constexpr (EPI == 0) {
        float* C = (float*)o0;
#pragma unroll
        for (int r = 0; r < 4; ++r)
          C[(size_t)(row + r) * 2048 + col] = acc[mi][ni][r] + bv;
      } else {
        if (col < 4096) {
          unsigned short* dh; unsigned short* dl; int cc;
          if (col < 2048) { dh = (unsigned short*)o0; dl = (unsigned short*)o1; cc = col; }
          else            { dh = (unsigned short*)o2; dl = (unsigned short*)o3; cc = col - 2048; }
#pragma unroll
          for (int r = 0; r < 4; ++r) {
            float v = acc[mi][ni][r] + bv;
            unsigned short h = f2b(v);
            unsigned short l = f2b(v - b2f(h));
            dh[(size_t)(row + r) * 2048 + cc] = h;
            dl[(size_t)(row + r) * 2048 + cc] = l;
          }
        } else {  // V^T [h*128+d][s]: 4 consecutive s per lane
          unsigned short* vt = (unsigned short*)o4;
          unsigned short hs[4];
#pragma unroll
          for (int r = 0; r < 4; ++r) hs[r] = f2b(acc[mi][ni][r] + bv);
          *(ushort4*)(vt + (size_t)(col - 4096) * 2048 + row) = make_ushort4(hs[0], hs[1], hs[2], hs[3]);
        }
      }
    }
  }
}

// ---------- flash attention (causal, no 1/sqrt(d) scaling — faithful to reference) ----------
// BQ=64 (4 waves x 16 rows), K-tiles of 64, d=128.
// Swapped-operand scheme: S^T = MFMA(K,Q) so each lane's 16 scores share ONE q-row (q=lane&15)
// -> softmax = local ops + 2 shfl_xor; O^T = MFMA(V,P) so rescale is lane-uniform.
__global__ __launch_bounds__(256, 2) void attn_fwd(
    const unsigned short* __restrict__ Qh, const unsigned short* __restrict__ Ql,
    const unsigned short* __restrict__ Kh, const unsigned short* __restrict__ Kl,
    const unsigned short* __restrict__ Vt, unsigned short* __restrict__ aout) {
  const int head = blockIdx.y;
  const int x = blockIdx.x;                       // 0..31
  // balance CUs: co-resident blocks (b, b+256) differ only in head by 8 -> opposite qt length
  const int qt = (head < 8) ? x : (31 - x);
  const int tid = threadIdx.x;
  const int wave = tid >> 6, lane = tid & 63;
  const int l16 = lane & 15, lq = lane >> 4;

  __shared__ unsigned short sKh[64 * 128];
  __shared__ unsigned short sKl[64 * 128];
  __shared__ unsigned short sV[128 * 64];         // [d][kseq]
  __shared__ unsigned short sP[4][16 * 72];       // per-wave P tile [q][k], stride 72

  const int q0 = qt * 64 + wave * 16;

  // hoist Q fragments (rows q0+l16, d chunks of 8) — used as MFMA B-operand
  bf16x8 qh[4], ql[4];
#pragma unroll
  for (int kc = 0; kc < 4; ++kc) {
    size_t off = (size_t)(q0 + l16) * 2048 + head * 128 + kc * 32 + lq * 8;
    qh[kc] = *(const bf16x8*)(Qh + off);
    ql[kc] = *(const bf16x8*)(Ql + off);
  }

  f32x4 o[8] = {};                 // O^T: [d = nd*16 + lq*4 + r][q = l16]
  float mst = -1e30f, lst = 0.f;   // online-softmax state for q = l16 (replicated over lq)

  const int ktmax = qt + 1;
  for (int kt = 0; kt < ktmax; ++kt) {
    // stage K hi/lo [64][128] and V^T [128][64], 8-chunk XOR swizzle per row
#pragma unroll
    for (int i = 0; i < 4; ++i) {
      int c = i * 256 + tid;
      {
        int row = c >> 4, cc = c & 15;
        int gc = ((cc ^ (row & 7)) << 3);
        size_t g = (size_t)(kt * 64 + row) * 2048 + head * 128 + gc;
        async_cp16(Kh + g, sKh + c * 8);
        async_cp16(Kl + g, sKl + c * 8);
      }
      {
        int row = c >> 3, cc = c & 7;
        int gc = ((cc ^ (row & 7)) << 3);
        size_t g = (size_t)(head * 128 + row) * 2048 + kt * 64 + gc;
        async_cp16(Vt + g, sV + c * 8);
      }
    }
    __syncthreads();

    // S^T[64 k][16 q] in 4 reg-tiles: s[nk] rows k = kt*64 + nk*16 + lq*4 + r, col q = l16
    f32x4 s[4] = {};
#pragma unroll
    for (int kc = 0; kc < 4; ++kc) {
#pragma unroll
      for (int nk = 0; nk < 4; ++nk) {
        int krow = nk * 16 + l16;
        int off = krow * 128 + ((((kc << 2) + lq) ^ (krow & 7)) << 3);
        bf16x8 kbh = *(const bf16x8*)(sKh + off);
        bf16x8 kbl = *(const bf16x8*)(sKl + off);
        s[nk] = MFMA16(kbh, qh[kc], s[nk]);   // Kh·Qh^T
        s[nk] = MFMA16(kbh, ql[kc], s[nk]);   // Kh·Ql^T
        s[nk] = MFMA16(kbl, qh[kc], s[nk]);   // Kl·Qh^T
      }
    }

    // causal mask + online softmax — all 16 scores in this lane belong to q = q0 + l16
    const int qg = q0 + l16;
    float pv[16];
    float mx = -1e30f;
#pragma unroll
    for (int nk = 0; nk < 4; ++nk)
#pragma unroll
      for (int r = 0; r < 4; ++r) {
        int kg = kt * 64 + nk * 16 + lq * 4 + r;
        float v = s[nk][r];
        if (kg > qg) v = -1e30f;
        pv[nk * 4 + r] = v;
        mx = fmaxf(mx, v);
      }
    mx = fmaxf(mx, __shfl_xor(mx, 16));
    mx = fmaxf(mx, __shfl_xor(mx, 32));
    float mnew = fmaxf(mst, mx);
    float scale = __expf(mst - mnew);
    float rsum = 0.f;
#pragma unroll
    for (int nk = 0; nk < 4; ++nk) {
      unsigned short pb[4];
#pragma unroll
      for (int r = 0; r < 4; ++r) {
        pb[r] = f2b(__expf(pv[nk * 4 + r] - mnew));
        rsum += b2f(pb[r]);
      }
      // P[q = l16][k = nk*16 + lq*4 .. +3], aligned 8B write, wave-private
      *(ushort4*)(&sP[wave][l16 * 72 + nk * 16 + lq * 4]) = make_ushort4(pb[0], pb[1], pb[2], pb[3]);
    }
    rsum += __shfl_xor(rsum, 16);
    rsum += __shfl_xor(rsum, 32);
    lst = lst * scale + rsum;
    mst = mnew;
#pragma unroll
    for (int nd = 0; nd < 8; ++nd) {
      o[nd][0] *= scale; o[nd][1] *= scale; o[nd][2] *= scale; o[nd][3] *= scale;
    }

    // O^T += V^T·P^T : A = V^T d-rows (from sV), B = P q-rows (from sP)
#pragma unroll
    for (int kc2 = 0; kc2 < 2; ++kc2) {
      bf16x8 pb = *(const bf16x8*)(&sP[wave][l16 * 72 + kc2 * 32 + lq * 8]);
#pragma unroll
      for (int nd = 0; nd < 8; ++nd) {
        int vrow = nd * 16 + l16;
        int off = vrow * 64 + ((((kc2 << 2) + lq) ^ (vrow & 7)) << 3);
        bf16x8 vb = *(const bf16x8*)(sV + off);
        o[nd] = MFMA16(vb, pb, o[nd]);
      }
    }
    __syncthreads();
  }

  const float norm = 1.f / lst;
#pragma unroll
  for (int nd = 0; nd < 8; ++nd) {
    unsigned short hs[4];
#pragma unroll
    for (int r = 0; r < 4; ++r) hs[r] = f2b(o[nd][r] * norm);
    *(ushort4*)(aout + (size_t)(q0 + l16) * 2048 + head * 128 + nd * 16 + lq * 4) =
        make_ushort4(hs[0], hs[1], hs[2], hs[3]);
  }
}

// ---------- launch ----------
extern "C" void kernel_launch(void* const* d_in, const int* in_sizes, int n_in,
                              void* d_out, int out_size, void* d_ws, size_t ws_size,
                              hipStream_t stream) {
  const float* x    = (const float*)d_in[0];
  const float* Wqkv = (const float*)d_in[1];
  const float* bqkv = (const float*)d_in[2];
  const float* Wout = (const float*)d_in[3];
  const float* bout = (const float*)d_in[4];
  float* out = (float*)d_out;

  unsigned short* w = (unsigned short*)d_ws;
  const size_t SZ = (size_t)2048 * 2048;
  unsigned short* xh  = w;  w += SZ;
  unsigned short* xl  = w;  w += SZ;
  unsigned short* wqh = w;  w += (size_t)6144 * 2048;
  unsigned short* wql = w;  w += (size_t)6144 * 2048;
  unsigned short* wo  = w;  w += SZ;
  unsigned short* qh  = w;  w += SZ;
  unsigned short* ql  = w;  w += SZ;
  unsigned short* kh  = w;  w += SZ;
  unsigned short* kl  = w;  w += SZ;
  unsigned short* vt  = w;  w += SZ;
  unsigned short* ao  = w;  w += SZ;
  (void)ws_size; (void)in_sizes; (void)n_in; (void)out_size;

  split_hi_lo<<<4096, 256, 0, stream>>>(x, xh, xl, (int)(SZ / 4));
  transpose_split<1><<<dim3(96, 32), 256, 0, stream>>>(Wqkv, wqh, wql, 2048, 6144);
  transpose_split<0><<<dim3(32, 32), 256, 0, stream>>>(Wout, wo, nullptr, 2048, 2048);
  // fused QKV projection: Q,K columns split-3; V columns 1-term into V^T layout
  gemm_bf16<4, 1><<<dim3(48, 16), 256, 0, stream>>>(xh, xl, wqh, wql, bqkv,
                                                    qh, ql, kh, kl, vt);
  attn_fwd<<<dim3(32, 16), 256, 0, stream>>>(qh, ql, kh, kl, vt, ao);
  gemm_bf16<8, 0><<<dim3(16, 16), 512, 0, stream>>>(ao, nullptr, wo, nullptr, bout, out,
                                                    nullptr, nullptr, nullptr, nullptr);
}

// Round 9
// 346.056 us; speedup vs baseline: 1.1982x; 1.0294x over previous
//
#include <hip/hip_runtime.h>
#include <stdint.h>

// ---------- types / helpers ----------
typedef __attribute__((ext_vector_type(8))) __bf16 bf16x8;   // MFMA A/B operand (4 VGPR)
typedef __attribute__((ext_vector_type(4))) float  f32x4;    // MFMA C/D operand

#define MFMA16(A, B, C) __builtin_amdgcn_mfma_f32_16x16x32_bf16((A), (B), (C), 0, 0, 0)

__device__ __forceinline__ unsigned short f2b(float f) {   // f32 -> bf16 RNE
  union { float f; uint32_t u; } c; c.f = f;
  uint32_t u = c.u;
  u += 0x7fffu + ((u >> 16) & 1u);
  return (unsigned short)(u >> 16);
}
__device__ __forceinline__ float b2f(unsigned short s) {
  union { uint32_t u; float f; } c; c.u = ((uint32_t)s) << 16;
  return c.f;
}
__device__ __forceinline__ void async_cp16(const void* g, void* l) {
  __builtin_amdgcn_global_load_lds((const __attribute__((address_space(1))) uint32_t*)g,
                                   (__attribute__((address_space(3))) uint32_t*)l, 16, 0, 0);
}

// ---------- elementwise: x -> hi/lo bf16 ----------
__global__ __launch_bounds__(256) void split_hi_lo(const float* __restrict__ in,
                                                   unsigned short* __restrict__ hi,
                                                   unsigned short* __restrict__ lo, int n4) {
  int i = blockIdx.x * 256 + threadIdx.x;
  if (i >= n4) return;
  const float4 v = ((const float4*)in)[i];
  float f[4] = {v.x, v.y, v.z, v.w};
  unsigned short hs[4], ls[4];
#pragma unroll
  for (int j = 0; j < 4; ++j) {
    hs[j] = f2b(f[j]);
    ls[j] = f2b(f[j] - b2f(hs[j]));
  }
  ((ushort4*)hi)[i] = make_ushort4(hs[0], hs[1], hs[2], hs[3]);
  ((ushort4*)lo)[i] = make_ushort4(ls[0], ls[1], ls[2], ls[3]);
}

// ---------- transpose + split: src[rows][cols] f32 -> dst[cols][rows] bf16 (hi, optional lo) ----------
template <int WLO>
__global__ __launch_bounds__(256) void transpose_split(const float* __restrict__ src,
                                                       unsigned short* __restrict__ dh,
                                                       unsigned short* __restrict__ dl,
                                                       int rows, int cols) {
  __shared__ float tile[64][65];
  const int r0 = blockIdx.y * 64, c0 = blockIdx.x * 64;
  const int t = threadIdx.x;
#pragma unroll
  for (int i = 0; i < 4; ++i) {
    int c = i * 256 + t;
    int rr = c >> 4, cc = (c & 15) << 2;
    const float4 v = *(const float4*)(src + (size_t)(r0 + rr) * cols + c0 + cc);
    tile[rr][cc] = v.x; tile[rr][cc + 1] = v.y; tile[rr][cc + 2] = v.z; tile[rr][cc + 3] = v.w;
  }
  __syncthreads();
#pragma unroll
  for (int i = 0; i < 4; ++i) {
    int c = i * 256 + t;
    int rr = c >> 4, cc = (c & 15) << 2;  // rr: out row (src col), cc: out col (src row)
    unsigned short hs[4], ls[4];
#pragma unroll
    for (int j = 0; j < 4; ++j) {
      float v = tile[cc + j][rr];
      hs[j] = f2b(v);
      ls[j] = f2b(v - b2f(hs[j]));
    }
    *(ushort4*)(dh + (size_t)(c0 + rr) * rows + r0 + cc) = make_ushort4(hs[0], hs[1], hs[2], hs[3]);
    if (WLO)
      *(ushort4*)(dl + (size_t)(c0 + rr) * rows + r0 + cc) = make_ushort4(ls[0], ls[1], ls[2], ls[3]);
  }
}

// ---------- 128x128-tile MFMA GEMM, K=2048, A[M][K], B[N][K] (pre-transposed) ----------
// NW: waves/block (4 -> 2x2 wave grid, 8 -> 2x4)
// EPI 0: f32 C[row*2048+col] + bias, 1-term.
// EPI 1: fused QKV. Blocks with n0<4096 run split-3 (Ah@Bh+Al@Bh+Ah@Bl) and write Q/K hi/lo;
//        blocks with n0>=4096 run 1-term and write V^T (o4[(col-4096)*2048 + row], bf16).
// LDS swizzle: slot (row,cc) holds global chunk cc^((row>>1)&3)  [conflict-free: 2 lanes/bank-group]
template <int NW, int EPI>
__global__ __launch_bounds__(NW * 64, 2) void gemm_bf16(
    const unsigned short* __restrict__ Ah, const unsigned short* __restrict__ Al,
    const unsigned short* __restrict__ Bh, const unsigned short* __restrict__ Bl,
    const float* __restrict__ bias,
    void* __restrict__ o0, void* __restrict__ o1, void* __restrict__ o2, void* __restrict__ o3,
    void* __restrict__ o4) {
  constexpr int K = 2048;
  constexpr int NBUF = (EPI == 1) ? 2 : 1;
  constexpr int WN = (NW == 8) ? 4 : 2;   // waves along N
  constexpr int WM = NW / WN;             // 2
  constexpr int MI = (128 / WM) / 16;     // 4
  constexpr int NI = (128 / WN) / 16;     // 4 (NW=4) or 2 (NW=8)
  __shared__ unsigned short sA[NBUF][128 * 32];
  __shared__ unsigned short sB[NBUF][128 * 32];
  const int tid = threadIdx.x;
  const int wave = tid >> 6, lane = tid & 63;
  const int l16 = lane & 15, lq = lane >> 4;
  const int wr = wave / WN, wc = wave % WN;
  const int m0 = blockIdx.y * 128, n0 = blockIdx.x * 128;
  const bool three = (EPI == 1) && (n0 < 4096);   // block-uniform

  f32x4 acc[MI][NI] = {};

  for (int k0 = 0; k0 < K; k0 += 32) {
#pragma unroll
    for (int i = 0; i < 512 / (NW * 64); ++i) {
      int c = i * (NW * 64) + tid;         // 512 chunks of 8 bf16 per tile
      int row = c >> 2, cc = c & 3;
      int gcol = ((cc ^ ((row >> 1) & 3)) << 3);
      size_t ga = (size_t)(m0 + row) * K + k0 + gcol;
      size_t gb = (size_t)(n0 + row) * K + k0 + gcol;
      async_cp16(Ah + ga, sA[0] + c * 8);
      async_cp16(Bh + gb, sB[0] + c * 8);
      if constexpr (EPI == 1) {
        if (three) {
          async_cp16(Al + ga, sA[1] + c * 8);
          async_cp16(Bl + gb, sB[1] + c * 8);
        }
      }
    }
    __syncthreads();

    bf16x8 ah[MI], al[MI], bh[NI], bl[NI];
#pragma unroll
    for (int mi = 0; mi < MI; ++mi) {
      int row = wr * (MI * 16) + mi * 16 + l16;
      int off = row * 32 + ((lq ^ ((row >> 1) & 3)) << 3);
      ah[mi] = *(const bf16x8*)(sA[0] + off);
      if constexpr (EPI == 1) {
        if (three) al[mi] = *(const bf16x8*)(sA[1] + off);
      }
    }
#pragma unroll
    for (int ni = 0; ni < NI; ++ni) {
      int row = wc * (NI * 16) + ni * 16 + l16;
      int off = row * 32 + ((lq ^ ((row >> 1) & 3)) << 3);
      bh[ni] = *(const bf16x8*)(sB[0] + off);
      if constexpr (EPI == 1) {
        if (three) bl[ni] = *(const bf16x8*)(sB[1] + off);
      }
    }
#pragma unroll
    for (int mi = 0; mi < MI; ++mi)
#pragma unroll
      for (int ni = 0; ni < NI; ++ni) {
        acc[mi][ni] = MFMA16(ah[mi], bh[ni], acc[mi][ni]);
        if constexpr (EPI == 1) {
          if (three) {
            acc[mi][ni] = MFMA16(al[mi], bh[ni], acc[mi][ni]);
            acc[mi][ni] = MFMA16(ah[mi], bl[ni], acc[mi][ni]);
          }
        }
      }
    __syncthreads();
  }

  // epilogue: C/D layout col=lane&15, row=(lane>>4)*4+reg (m89-verified)
#pragma unroll
  for (int mi = 0; mi < MI; ++mi) {
#pragma unroll
    for (int ni = 0; ni < NI; ++ni) {
      int row = m0 + wr * (MI * 16) + mi * 16 + lq * 4;
      int col = n0 + wc * (NI * 16) + ni * 16 + l16;
      float bv = bias[col];
      if constexpr (EPI == 0) {
        float* C = (float*)o0;
#pragma unroll
        for (int r = 0; r < 4; ++r)
          C[(size_t)(row + r) * 2048 + col] = acc[mi][ni][r] + bv;
      } else {
        if (col < 4096) {
          unsigned short* dh; unsigned short* dl; int cc;
          if (col < 2048) { dh = (unsigned short*)o0; dl = (unsigned short*)o1; cc = col; }
          else            { dh = (unsigned short*)o2; dl = (unsigned short*)o3; cc = col - 2048; }
#pragma unroll
          for (int r = 0; r < 4; ++r) {
            float v = acc[mi][ni][r] + bv;
            unsigned short h = f2b(v);
            unsigned short l = f2b(v - b2f(h));
            dh[(size_t)(row + r) * 2048 + cc] = h;
            dl[(size_t)(row + r) * 2048 + cc] = l;
          }
        } else {  // V^T [h*128+d][s]: 4 consecutive s per lane
          unsigned short* vt = (unsigned short*)o4;
          unsigned short hs[4];
#pragma unroll
          for (int r = 0; r < 4; ++r) hs[r] = f2b(acc[mi][ni][r] + bv);
          *(ushort4*)(vt + (size_t)(col - 4096) * 2048 + row) = make_ushort4(hs[0], hs[1], hs[2], hs[3]);
        }
      }
    }
  }
}

// ---------- flash attention (causal, no 1/sqrt(d) scaling — faithful to reference) ----------
// BQ=64 (4 waves x 16 rows), K-tiles of 64, d=128.
// Swapped-operand scheme: S^T = MFMA(K,Q); q-row = lane&15 -> softmax local + 2 shfl_xor.
// 2-term logits: S = Kh·(Qh+Ql)  [K-lo term dropped: adds ~0.013 logit std, sens-damped ~0.02 absmax]
// -> Kl never staged: 8 gload_lds/thread/tile (was 12), LDS 41.2KB.
__global__ __launch_bounds__(256, 2) void attn_fwd(
    const unsigned short* __restrict__ Qh, const unsigned short* __restrict__ Ql,
    const unsigned short* __restrict__ Kh, const unsigned short* __restrict__ Kl,
    const unsigned short* __restrict__ Vt, unsigned short* __restrict__ aout) {
  const int head = blockIdx.y;
  const int x = blockIdx.x;                       // 0..31
  // balance CUs: co-resident blocks (b, b+256) differ only in head by 8 -> opposite qt length
  const int qt = (head < 8) ? x : (31 - x);
  const int tid = threadIdx.x;
  const int wave = tid >> 6, lane = tid & 63;
  const int l16 = lane & 15, lq = lane >> 4;
  (void)Kl;

  __shared__ unsigned short sKh[64 * 128];
  __shared__ unsigned short sV[128 * 64];         // [d][kseq]
  __shared__ unsigned short sP[4][16 * 72];       // per-wave P tile [q][k], stride 72

  const int q0 = qt * 64 + wave * 16;

  // hoist Q fragments (rows q0+l16, d chunks of 8) — used as MFMA B-operand
  bf16x8 qh[4], ql[4];
#pragma unroll
  for (int kc = 0; kc < 4; ++kc) {
    size_t off = (size_t)(q0 + l16) * 2048 + head * 128 + kc * 32 + lq * 8;
    qh[kc] = *(const bf16x8*)(Qh + off);
    ql[kc] = *(const bf16x8*)(Ql + off);
  }

  f32x4 o[8] = {};                 // O^T: [d = nd*16 + lq*4 + r][q = l16]
  float mst = -1e30f, lst = 0.f;   // online-softmax state for q = l16 (replicated over lq)

  const int ktmax = qt + 1;
  for (int kt = 0; kt < ktmax; ++kt) {
    // stage K hi [64][128] and V^T [128][64], 8-chunk XOR swizzle per row
#pragma unroll
    for (int i = 0; i < 4; ++i) {
      int c = i * 256 + tid;
      {
        int row = c >> 4, cc = c & 15;
        int gc = ((cc ^ (row & 7)) << 3);
        size_t g = (size_t)(kt * 64 + row) * 2048 + head * 128 + gc;
        async_cp16(Kh + g, sKh + c * 8);
      }
      {
        int row = c >> 3, cc = c & 7;
        int gc = ((cc ^ (row & 7)) << 3);
        size_t g = (size_t)(head * 128 + row) * 2048 + kt * 64 + gc;
        async_cp16(Vt + g, sV + c * 8);
      }
    }
    __syncthreads();

    // S^T[64 k][16 q] in 4 reg-tiles: s[nk] rows k = kt*64 + nk*16 + lq*4 + r, col q = l16
    f32x4 s[4] = {};
    __builtin_amdgcn_s_setprio(1);
#pragma unroll
    for (int kc = 0; kc < 4; ++kc) {
#pragma unroll
      for (int nk = 0; nk < 4; ++nk) {
        int krow = nk * 16 + l16;
        int off = krow * 128 + ((((kc << 2) + lq) ^ (krow & 7)) << 3);
        bf16x8 kbh = *(const bf16x8*)(sKh + off);
        s[nk] = MFMA16(kbh, qh[kc], s[nk]);   // Kh·Qh^T
        s[nk] = MFMA16(kbh, ql[kc], s[nk]);   // Kh·Ql^T
      }
    }
    __builtin_amdgcn_s_setprio(0);

    // causal mask + online softmax — all 16 scores in this lane belong to q = q0 + l16
    const int qg = q0 + l16;
    float pv[16];
    float mx = -1e30f;
#pragma unroll
    for (int nk = 0; nk < 4; ++nk)
#pragma unroll
      for (int r = 0; r < 4; ++r) {
        int kg = kt * 64 + nk * 16 + lq * 4 + r;
        float v = s[nk][r];
        if (kg > qg) v = -1e30f;
        pv[nk * 4 + r] = v;
        mx = fmaxf(mx, v);
      }
    mx = fmaxf(mx, __shfl_xor(mx, 16));
    mx = fmaxf(mx, __shfl_xor(mx, 32));
    float mnew = fmaxf(mst, mx);
    float scale = __expf(mst - mnew);
    float rsum = 0.f;
#pragma unroll
    for (int nk = 0; nk < 4; ++nk) {
      unsigned short pb[4];
#pragma unroll
      for (int r = 0; r < 4; ++r) {
        pb[r] = f2b(__expf(pv[nk * 4 + r] - mnew));
        rsum += b2f(pb[r]);
      }
      // P[q = l16][k = nk*16 + lq*4 .. +3], aligned 8B write, wave-private
      *(ushort4*)(&sP[wave][l16 * 72 + nk * 16 + lq * 4]) = make_ushort4(pb[0], pb[1], pb[2], pb[3]);
    }
    rsum += __shfl_xor(rsum, 16);
    rsum += __shfl_xor(rsum, 32);
    lst = lst * scale + rsum;
    mst = mnew;
#pragma unroll
    for (int nd = 0; nd < 8; ++nd) {
      o[nd][0] *= scale; o[nd][1] *= scale; o[nd][2] *= scale; o[nd][3] *= scale;
    }

    // O^T += V^T·P^T : A = V^T d-rows (from sV), B = P q-rows (from sP)
    __builtin_amdgcn_s_setprio(1);
#pragma unroll
    for (int kc2 = 0; kc2 < 2; ++kc2) {
      bf16x8 pb = *(const bf16x8*)(&sP[wave][l16 * 72 + kc2 * 32 + lq * 8]);
#pragma unroll
      for (int nd = 0; nd < 8; ++nd) {
        int vrow = nd * 16 + l16;
        int off = vrow * 64 + ((((kc2 << 2) + lq) ^ (vrow & 7)) << 3);
        bf16x8 vb = *(const bf16x8*)(sV + off);
        o[nd] = MFMA16(vb, pb, o[nd]);
      }
    }
    __builtin_amdgcn_s_setprio(0);
    __syncthreads();
  }

  const float norm = 1.f / lst;
#pragma unroll
  for (int nd = 0; nd < 8; ++nd) {
    unsigned short hs[4];
#pragma unroll
    for (int r = 0; r < 4; ++r) hs[r] = f2b(o[nd][r] * norm);
    *(ushort4*)(aout + (size_t)(q0 + l16) * 2048 + head * 128 + nd * 16 + lq * 4) =
        make_ushort4(hs[0], hs[1], hs[2], hs[3]);
  }
}

// ---------- launch ----------
extern "C" void kernel_launch(void* const* d_in, const int* in_sizes, int n_in,
                              void* d_out, int out_size, void* d_ws, size_t ws_size,
                              hipStream_t stream) {
  const float* x    = (const float*)d_in[0];
  const float* Wqkv = (const float*)d_in[1];
  const float* bqkv = (const float*)d_in[2];
  const float* Wout = (const float*)d_in[3];
  const float* bout = (const float*)d_in[4];
  float* out = (float*)d_out;

  unsigned short* w = (unsigned short*)d_ws;
  const size_t SZ = (size_t)2048 * 2048;
  unsigned short* xh  = w;  w += SZ;
  unsigned short* xl  = w;  w += SZ;
  unsigned short* wqh = w;  w += (size_t)6144 * 2048;
  unsigned short* wql = w;  w += (size_t)6144 * 2048;
  unsigned short* wo  = w;  w += SZ;
  unsigned short* qh  = w;  w += SZ;
  unsigned short* ql  = w;  w += SZ;
  unsigned short* kh  = w;  w += SZ;
  unsigned short* kl  = w;  w += SZ;
  unsigned short* vt  = w;  w += SZ;
  unsigned short* ao  = w;  w += SZ;
  (void)ws_size; (void)in_sizes; (void)n_in; (void)out_size;

  split_hi_lo<<<4096, 256, 0, stream>>>(x, xh, xl, (int)(SZ / 4));
  transpose_split<1><<<dim3(96, 32), 256, 0, stream>>>(Wqkv, wqh, wql, 2048, 6144);
  transpose_split<0><<<dim3(32, 32), 256, 0, stream>>>(Wout, wo, nullptr, 2048, 2048);
  // fused QKV projection: Q,K columns split-3; V columns 1-term into V^T layout
  gemm_bf16<4, 1><<<dim3(48, 16), 256, 0, stream>>>(xh, xl, wqh, wql, bqkv,
                                                    qh, ql, kh, kl, vt);
  attn_fwd<<<dim3(32, 16), 256, 0, stream>>>(qh, ql, kh, kl, vt, ao);
  gemm_bf16<8, 0><<<dim3(16, 16), 512, 0, stream>>>(ao, nullptr, wo, nullptr, bout, out,
                                                    nullptr, nullptr, nullptr, nullptr);
}

// Round 10
// 314.785 us; speedup vs baseline: 1.3172x; 1.0993x over previous
//
#include <hip/hip_runtime.h>
#include <stdint.h>

// ---------- types / helpers ----------
typedef __attribute__((ext_vector_type(8))) __bf16 bf16x8;   // MFMA A/B operand (4 VGPR)
typedef __attribute__((ext_vector_type(4))) float  f32x4;    // MFMA C/D operand

#define MFMA16(A, B, C) __builtin_amdgcn_mfma_f32_16x16x32_bf16((A), (B), (C), 0, 0, 0)

__device__ __forceinline__ unsigned short f2b(float f) {   // f32 -> bf16 RNE
  union { float f; uint32_t u; } c; c.f = f;
  uint32_t u = c.u;
  u += 0x7fffu + ((u >> 16) & 1u);
  return (unsigned short)(u >> 16);
}
__device__ __forceinline__ float b2f(unsigned short s) {
  union { uint32_t u; float f; } c; c.u = ((uint32_t)s) << 16;
  return c.f;
}
__device__ __forceinline__ void async_cp16(const void* g, void* l) {
  __builtin_amdgcn_global_load_lds((const __attribute__((address_space(1))) uint32_t*)g,
                                   (__attribute__((address_space(3))) uint32_t*)l, 16, 0, 0);
}

// ---------- elementwise: x -> hi/lo bf16 ----------
__global__ __launch_bounds__(256) void split_hi_lo(const float* __restrict__ in,
                                                   unsigned short* __restrict__ hi,
                                                   unsigned short* __restrict__ lo, int n4) {
  int i = blockIdx.x * 256 + threadIdx.x;
  if (i >= n4) return;
  const float4 v = ((const float4*)in)[i];
  float f[4] = {v.x, v.y, v.z, v.w};
  unsigned short hs[4], ls[4];
#pragma unroll
  for (int j = 0; j < 4; ++j) {
    hs[j] = f2b(f[j]);
    ls[j] = f2b(f[j] - b2f(hs[j]));
  }
  ((ushort4*)hi)[i] = make_ushort4(hs[0], hs[1], hs[2], hs[3]);
  ((ushort4*)lo)[i] = make_ushort4(ls[0], ls[1], ls[2], ls[3]);
}

// ---------- transpose + split: src[rows][cols] f32 -> dst[cols][rows] bf16 (hi, optional lo) ----------
template <int WLO>
__global__ __launch_bounds__(256) void transpose_split(const float* __restrict__ src,
                                                       unsigned short* __restrict__ dh,
                                                       unsigned short* __restrict__ dl,
                                                       int rows, int cols) {
  __shared__ float tile[64][65];
  const int r0 = blockIdx.y * 64, c0 = blockIdx.x * 64;
  const int t = threadIdx.x;
#pragma unroll
  for (int i = 0; i < 4; ++i) {
    int c = i * 256 + t;
    int rr = c >> 4, cc = (c & 15) << 2;
    const float4 v = *(const float4*)(src + (size_t)(r0 + rr) * cols + c0 + cc);
    tile[rr][cc] = v.x; tile[rr][cc + 1] = v.y; tile[rr][cc + 2] = v.z; tile[rr][cc + 3] = v.w;
  }
  __syncthreads();
#pragma unroll
  for (int i = 0; i < 4; ++i) {
    int c = i * 256 + t;
    int rr = c >> 4, cc = (c & 15) << 2;  // rr: out row (src col), cc: out col (src row)
    unsigned short hs[4], ls[4];
#pragma unroll
    for (int j = 0; j < 4; ++j) {
      float v = tile[cc + j][rr];
      hs[j] = f2b(v);
      ls[j] = f2b(v - b2f(hs[j]));
    }
    *(ushort4*)(dh + (size_t)(c0 + rr) * rows + r0 + cc) = make_ushort4(hs[0], hs[1], hs[2], hs[3]);
    if (WLO)
      *(ushort4*)(dl + (size_t)(c0 + rr) * rows + r0 + cc) = make_ushort4(ls[0], ls[1], ls[2], ls[3]);
  }
}

// ---------- 128x128-tile MFMA GEMM, K=2048, A[M][K], B[N][K] (pre-transposed) ----------
// NW: waves/block (4 -> 2x2 wave grid, 8 -> 2x4)
// EPI 0: f32 C[row*2048+col] + bias, 1-term.
// EPI 1: fused QKV, 2-term. Blocks with n0<4096 run (Ah+Al)@Bh and write Q/K hi/lo;
//        blocks with n0>=4096 run 1-term Ah@Bh and write V^T (o4[(col-4096)*2048 + row], bf16).
//        (W-lo term dropped: adds ~0.0125 logit std per operand, validated error model r9)
// LDS swizzle: slot (row,cc) holds global chunk cc^((row>>1)&3)  [conflict-free: 2 lanes/bank-group]
template <int NW, int EPI>
__global__ __launch_bounds__(NW * 64, 2) void gemm_bf16(
    const unsigned short* __restrict__ Ah, const unsigned short* __restrict__ Al,
    const unsigned short* __restrict__ Bh,
    const float* __restrict__ bias,
    void* __restrict__ o0, void* __restrict__ o1, void* __restrict__ o2, void* __restrict__ o3,
    void* __restrict__ o4) {
  constexpr int K = 2048;
  constexpr int NBUFA = (EPI == 1) ? 2 : 1;
  constexpr int WN = (NW == 8) ? 4 : 2;   // waves along N
  constexpr int WM = NW / WN;             // 2
  constexpr int MI = (128 / WM) / 16;     // 4
  constexpr int NI = (128 / WN) / 16;     // 4 (NW=4) or 2 (NW=8)
  __shared__ unsigned short sA[NBUFA][128 * 32];
  __shared__ unsigned short sB[128 * 32];
  const int tid = threadIdx.x;
  const int wave = tid >> 6, lane = tid & 63;
  const int l16 = lane & 15, lq = lane >> 4;
  const int wr = wave / WN, wc = wave % WN;
  const int m0 = blockIdx.y * 128, n0 = blockIdx.x * 128;
  const bool two = (EPI == 1) && (n0 < 4096);   // block-uniform

  f32x4 acc[MI][NI] = {};

  for (int k0 = 0; k0 < K; k0 += 32) {
#pragma unroll
    for (int i = 0; i < 512 / (NW * 64); ++i) {
      int c = i * (NW * 64) + tid;         // 512 chunks of 8 bf16 per tile
      int row = c >> 2, cc = c & 3;
      int gcol = ((cc ^ ((row >> 1) & 3)) << 3);
      size_t ga = (size_t)(m0 + row) * K + k0 + gcol;
      size_t gb = (size_t)(n0 + row) * K + k0 + gcol;
      async_cp16(Ah + ga, sA[0] + c * 8);
      async_cp16(Bh + gb, sB + c * 8);
      if constexpr (EPI == 1) {
        if (two) async_cp16(Al + ga, sA[1] + c * 8);
      }
    }
    __syncthreads();

    bf16x8 ah[MI], al[MI], bh[NI];
#pragma unroll
    for (int mi = 0; mi < MI; ++mi) {
      int row = wr * (MI * 16) + mi * 16 + l16;
      int off = row * 32 + ((lq ^ ((row >> 1) & 3)) << 3);
      ah[mi] = *(const bf16x8*)(sA[0] + off);
      if constexpr (EPI == 1) {
        if (two) al[mi] = *(const bf16x8*)(sA[1] + off);
      }
    }
#pragma unroll
    for (int ni = 0; ni < NI; ++ni) {
      int row = wc * (NI * 16) + ni * 16 + l16;
      int off = row * 32 + ((lq ^ ((row >> 1) & 3)) << 3);
      bh[ni] = *(const bf16x8*)(sB + off);
    }
#pragma unroll
    for (int mi = 0; mi < MI; ++mi)
#pragma unroll
      for (int ni = 0; ni < NI; ++ni) {
        acc[mi][ni] = MFMA16(ah[mi], bh[ni], acc[mi][ni]);
        if constexpr (EPI == 1) {
          if (two) acc[mi][ni] = MFMA16(al[mi], bh[ni], acc[mi][ni]);
        }
      }
    __syncthreads();
  }

  // epilogue: C/D layout col=lane&15, row=(lane>>4)*4+reg (m89-verified)
#pragma unroll
  for (int mi = 0; mi < MI; ++mi) {
#pragma unroll
    for (int ni = 0; ni < NI; ++ni) {
      int row = m0 + wr * (MI * 16) + mi * 16 + lq * 4;
      int col = n0 + wc * (NI * 16) + ni * 16 + l16;
      float bv = bias[col];
      if constexpr (EPI == 0) {
        float* C = (float*)o0;
#pragma unroll
        for (int r = 0; r < 4; ++r)
          C[(size_t)(row + r) * 2048 + col] = acc[mi][ni][r] + bv;
      } else {
        if (col < 4096) {
          unsigned short* dh; unsigned short* dl; int cc;
          if (col < 2048) { dh = (unsigned short*)o0; dl = (unsigned short*)o1; cc = col; }
          else            { dh = (unsigned short*)o2; dl = (unsigned short*)o3; cc = col - 2048; }
#pragma unroll
          for (int r = 0; r < 4; ++r) {
            float v = acc[mi][ni][r] + bv;
            unsigned short h = f2b(v);
            unsigned short l = f2b(v - b2f(h));
            dh[(size_t)(row + r) * 2048 + cc] = h;
            dl[(size_t)(row + r) * 2048 + cc] = l;
          }
        } else {  // V^T [h*128+d][s]: 4 consecutive s per lane
          unsigned short* vt = (unsigned short*)o4;
          unsigned short hs[4];
#pragma unroll
          for (int r = 0; r < 4; ++r) hs[r] = f2b(acc[mi][ni][r] + bv);
          *(ushort4*)(vt + (size_t)(col - 4096) * 2048 + row) = make_ushort4(hs[0], hs[1], hs[2], hs[3]);
        }
      }
    }
  }
}

// ---------- flash attention (causal, no 1/sqrt(d) scaling — faithful to reference) ----------
// BQ=64 (4 waves x 16 rows), K-tiles of 64, d=128.
// Swapped-operand scheme: S^T = MFMA(K,Q); q-row = lane&15 -> softmax local + 2 shfl_xor.
// 2-term logits: S = Kh·(Qh+Ql)  [K-lo term dropped; validated r9: absmax 0.047]
__global__ __launch_bounds__(256, 2) void attn_fwd(
    const unsigned short* __restrict__ Qh, const unsigned short* __restrict__ Ql,
    const unsigned short* __restrict__ Kh,
    const unsigned short* __restrict__ Vt, unsigned short* __restrict__ aout) {
  const int head = blockIdx.y;
  const int x = blockIdx.x;                       // 0..31
  // balance CUs: co-resident blocks (b, b+256) differ only in head by 8 -> opposite qt length
  const int qt = (head < 8) ? x : (31 - x);
  const int tid = threadIdx.x;
  const int wave = tid >> 6, lane = tid & 63;
  const int l16 = lane & 15, lq = lane >> 4;

  __shared__ unsigned short sKh[64 * 128];
  __shared__ unsigned short sV[128 * 64];         // [d][kseq]
  __shared__ unsigned short sP[4][16 * 72];       // per-wave P tile [q][k], stride 72

  const int q0 = qt * 64 + wave * 16;

  // hoist Q fragments (rows q0+l16, d chunks of 8) — used as MFMA B-operand
  bf16x8 qh[4], ql[4];
#pragma unroll
  for (int kc = 0; kc < 4; ++kc) {
    size_t off = (size_t)(q0 + l16) * 2048 + head * 128 + kc * 32 + lq * 8;
    qh[kc] = *(const bf16x8*)(Qh + off);
    ql[kc] = *(const bf16x8*)(Ql + off);
  }

  f32x4 o[8] = {};                 // O^T: [d = nd*16 + lq*4 + r][q = l16]
  float mst = -1e30f, lst = 0.f;   // online-softmax state for q = l16 (replicated over lq)

  const int ktmax = qt + 1;
  for (int kt = 0; kt < ktmax; ++kt) {
    // stage K hi [64][128] and V^T [128][64], 8-chunk XOR swizzle per row
#pragma unroll
    for (int i = 0; i < 4; ++i) {
      int c = i * 256 + tid;
      {
        int row = c >> 4, cc = c & 15;
        int gc = ((cc ^ (row & 7)) << 3);
        size_t g = (size_t)(kt * 64 + row) * 2048 + head * 128 + gc;
        async_cp16(Kh + g, sKh + c * 8);
      }
      {
        int row = c >> 3, cc = c & 7;
        int gc = ((cc ^ (row & 7)) << 3);
        size_t g = (size_t)(head * 128 + row) * 2048 + kt * 64 + gc;
        async_cp16(Vt + g, sV + c * 8);
      }
    }
    __syncthreads();

    // S^T[64 k][16 q] in 4 reg-tiles: s[nk] rows k = kt*64 + nk*16 + lq*4 + r, col q = l16
    f32x4 s[4] = {};
    __builtin_amdgcn_s_setprio(1);
#pragma unroll
    for (int kc = 0; kc < 4; ++kc) {
#pragma unroll
      for (int nk = 0; nk < 4; ++nk) {
        int krow = nk * 16 + l16;
        int off = krow * 128 + ((((kc << 2) + lq) ^ (krow & 7)) << 3);
        bf16x8 kbh = *(const bf16x8*)(sKh + off);
        s[nk] = MFMA16(kbh, qh[kc], s[nk]);   // Kh·Qh^T
        s[nk] = MFMA16(kbh, ql[kc], s[nk]);   // Kh·Ql^T
      }
    }
    __builtin_amdgcn_s_setprio(0);

    // causal mask + online softmax — all 16 scores in this lane belong to q = q0 + l16
    const int qg = q0 + l16;
    float pv[16];
    float mx = -1e30f;
#pragma unroll
    for (int nk = 0; nk < 4; ++nk)
#pragma unroll
      for (int r = 0; r < 4; ++r) {
        int kg = kt * 64 + nk * 16 + lq * 4 + r;
        float v = s[nk][r];
        if (kg > qg) v = -1e30f;
        pv[nk * 4 + r] = v;
        mx = fmaxf(mx, v);
      }
    mx = fmaxf(mx, __shfl_xor(mx, 16));
    mx = fmaxf(mx, __shfl_xor(mx, 32));
    float mnew = fmaxf(mst, mx);
    float scale = __expf(mst - mnew);
    float rsum = 0.f;
#pragma unroll
    for (int nk = 0; nk < 4; ++nk) {
      unsigned short pb[4];
#pragma unroll
      for (int r = 0; r < 4; ++r) {
        pb[r] = f2b(__expf(pv[nk * 4 + r] - mnew));
        rsum += b2f(pb[r]);
      }
      // P[q = l16][k = nk*16 + lq*4 .. +3], aligned 8B write, wave-private
      *(ushort4*)(&sP[wave][l16 * 72 + nk * 16 + lq * 4]) = make_ushort4(pb[0], pb[1], pb[2], pb[3]);
    }
    rsum += __shfl_xor(rsum, 16);
    rsum += __shfl_xor(rsum, 32);
    lst = lst * scale + rsum;
    mst = mnew;
#pragma unroll
    for (int nd = 0; nd < 8; ++nd) {
      o[nd][0] *= scale; o[nd][1] *= scale; o[nd][2] *= scale; o[nd][3] *= scale;
    }

    // O^T += V^T·P^T : A = V^T d-rows (from sV), B = P q-rows (from sP)
    __builtin_amdgcn_s_setprio(1);
#pragma unroll
    for (int kc2 = 0; kc2 < 2; ++kc2) {
      bf16x8 pb = *(const bf16x8*)(&sP[wave][l16 * 72 + kc2 * 32 + lq * 8]);
#pragma unroll
      for (int nd = 0; nd < 8; ++nd) {
        int vrow = nd * 16 + l16;
        int off = vrow * 64 + ((((kc2 << 2) + lq) ^ (vrow & 7)) << 3);
        bf16x8 vb = *(const bf16x8*)(sV + off);
        o[nd] = MFMA16(vb, pb, o[nd]);
      }
    }
    __builtin_amdgcn_s_setprio(0);
    __syncthreads();
  }

  const float norm = 1.f / lst;
#pragma unroll
  for (int nd = 0; nd < 8; ++nd) {
    unsigned short hs[4];
#pragma unroll
    for (int r = 0; r < 4; ++r) hs[r] = f2b(o[nd][r] * norm);
    *(ushort4*)(aout + (size_t)(q0 + l16) * 2048 + head * 128 + nd * 16 + lq * 4) =
        make_ushort4(hs[0], hs[1], hs[2], hs[3]);
  }
}

// ---------- launch ----------
extern "C" void kernel_launch(void* const* d_in, const int* in_sizes, int n_in,
                              void* d_out, int out_size, void* d_ws, size_t ws_size,
                              hipStream_t stream) {
  const float* x    = (const float*)d_in[0];
  const float* Wqkv = (const float*)d_in[1];
  const float* bqkv = (const float*)d_in[2];
  const float* Wout = (const float*)d_in[3];
  const float* bout = (const float*)d_in[4];
  float* out = (float*)d_out;

  unsigned short* w = (unsigned short*)d_ws;
  const size_t SZ = (size_t)2048 * 2048;
  unsigned short* xh  = w;  w += SZ;
  unsigned short* xl  = w;  w += SZ;
  unsigned short* wqh = w;  w += (size_t)6144 * 2048;
  unsigned short* wo  = w;  w += SZ;
  unsigned short* qh  = w;  w += SZ;
  unsigned short* ql  = w;  w += SZ;
  unsigned short* kh  = w;  w += SZ;
  unsigned short* kl  = w;  w += SZ;
  unsigned short* vt  = w;  w += SZ;
  unsigned short* ao  = w;  w += SZ;
  (void)ws_size; (void)in_sizes; (void)n_in; (void)out_size; (void)kl;

  split_hi_lo<<<4096, 256, 0, stream>>>(x, xh, xl, (int)(SZ / 4));
  transpose_split<0><<<dim3(96, 32), 256, 0, stream>>>(Wqkv, wqh, nullptr, 2048, 6144);
  transpose_split<0><<<dim3(32, 32), 256, 0, stream>>>(Wout, wo, nullptr, 2048, 2048);
  // fused QKV projection: Q,K columns 2-term (xh+xl)@Wh; V columns 1-term into V^T layout
  gemm_bf16<4, 1><<<dim3(48, 16), 256, 0, stream>>>(xh, xl, wqh, bqkv,
                                                    qh, ql, kh, kl, vt);
  attn_fwd<<<dim3(32, 16), 256, 0, stream>>>(qh, ql, kh, vt, ao);
  gemm_bf16<8, 0><<<dim3(16, 16), 512, 0, stream>>>(ao, nullptr, wo, bout, out,
                                                    nullptr, nullptr, nullptr, nullptr);
}

// Round 14
// 301.460 us; speedup vs baseline: 1.3754x; 1.0442x over previous
//
#include <hip/hip_runtime.h>
#include <stdint.h>

// ---------- types / helpers ----------
typedef __attribute__((ext_vector_type(8))) __bf16 bf16x8;   // MFMA A/B operand (4 VGPR)
typedef __attribute__((ext_vector_type(4))) float  f32x4;    // MFMA C/D operand

#define MFMA16(A, B, C) __builtin_amdgcn_mfma_f32_16x16x32_bf16((A), (B), (C), 0, 0, 0)

__device__ __forceinline__ unsigned short f2b(float f) {   // f32 -> bf16 RNE
  union { float f; uint32_t u; } c; c.f = f;
  uint32_t u = c.u;
  u += 0x7fffu + ((u >> 16) & 1u);
  return (unsigned short)(u >> 16);
}
__device__ __forceinline__ float b2f(unsigned short s) {
  union { uint32_t u; float f; } c; c.u = ((uint32_t)s) << 16;
  return c.f;
}
__device__ __forceinline__ void async_cp16(const void* g, void* l) {
  __builtin_amdgcn_global_load_lds((const __attribute__((address_space(1))) uint32_t*)g,
                                   (__attribute__((address_space(3))) uint32_t*)l, 16, 0, 0);
}

// ---------- fused preprocessing: split x -> hi/lo ; transpose Wqkv -> wqh ; transpose Wout -> wo
// grid layout: [0,4096) split ; [4096,7168) Wqkv transpose (96x32) ; [7168,8192) Wout (32x32)
__device__ __forceinline__ void transpose_body(const float* __restrict__ src,
                                               unsigned short* __restrict__ dh,
                                               int rows, int cols, int bx, int by,
                                               float (*tile)[65], int t) {
  const int r0 = by * 64, c0 = bx * 64;
#pragma unroll
  for (int i = 0; i < 4; ++i) {
    int c = i * 256 + t;
    int rr = c >> 4, cc = (c & 15) << 2;
    const float4 v = *(const float4*)(src + (size_t)(r0 + rr) * cols + c0 + cc);
    tile[rr][cc] = v.x; tile[rr][cc + 1] = v.y; tile[rr][cc + 2] = v.z; tile[rr][cc + 3] = v.w;
  }
  __syncthreads();
#pragma unroll
  for (int i = 0; i < 4; ++i) {
    int c = i * 256 + t;
    int rr = c >> 4, cc = (c & 15) << 2;  // rr: out row (src col), cc: out col (src row)
    unsigned short hs[4];
#pragma unroll
    for (int j = 0; j < 4; ++j) hs[j] = f2b(tile[cc + j][rr]);
    *(ushort4*)(dh + (size_t)(c0 + rr) * rows + r0 + cc) = make_ushort4(hs[0], hs[1], hs[2], hs[3]);
  }
}

__global__ __launch_bounds__(256) void preprocess(
    const float* __restrict__ x, unsigned short* __restrict__ xh, unsigned short* __restrict__ xl,
    const float* __restrict__ Wqkv, unsigned short* __restrict__ wqh,
    const float* __restrict__ Wout, unsigned short* __restrict__ wo) {
  __shared__ float tile[64][65];
  const int b = blockIdx.x;
  const int t = threadIdx.x;
  if (b < 4096) {                       // x -> hi/lo bf16, 4 f32 per thread
    int i = b * 256 + t;
    const float4 v = ((const float4*)x)[i];
    float f[4] = {v.x, v.y, v.z, v.w};
    unsigned short hs[4], ls[4];
#pragma unroll
    for (int j = 0; j < 4; ++j) {
      hs[j] = f2b(f[j]);
      ls[j] = f2b(f[j] - b2f(hs[j]));
    }
    ((ushort4*)xh)[i] = make_ushort4(hs[0], hs[1], hs[2], hs[3]);
    ((ushort4*)xl)[i] = make_ushort4(ls[0], ls[1], ls[2], ls[3]);
  } else if (b < 7168) {                // Wqkv [2048][6144] -> wqh [6144][2048]
    int bb = b - 4096;
    transpose_body(Wqkv, wqh, 2048, 6144, bb % 96, bb / 96, tile, t);
  } else {                              // Wout [2048][2048] -> wo [2048][2048]^T
    int bb = b - 7168;
    transpose_body(Wout, wo, 2048, 2048, bb % 32, bb / 32, tile, t);
  }
}

// ---------- 128x128-tile MFMA GEMM, K=2048, BK=64, A[M][K], B[N][K] (pre-transposed) ----------
// NW: waves/block (4 -> 2x2 wave grid, 8 -> 2x4)
// EPI 0: f32 C[row*2048+col] + bias, 1-term.
// EPI 1: fused QKV, 2-term. n0<4096: (Ah+Al)@Bh -> Q/K hi/lo; n0>=4096: Ah@Bh -> V^T.
// BK=64: one barrier-pair per 64 k (halves drains vs BK=32).
// LDS swizzle: slot (row,cc) holds global chunk cc^(row&7) — attn-sV-proven conflict-free
// (row stride 128B, 8 slots; measured 0 conflicts r7-r10).
template <int NW, int EPI>
__global__ __launch_bounds__(NW * 64, 2) void gemm_bf16(
    const unsigned short* __restrict__ Ah, const unsigned short* __restrict__ Al,
    const unsigned short* __restrict__ Bh,
    const float* __restrict__ bias,
    void* __restrict__ o0, void* __restrict__ o1, void* __restrict__ o2, void* __restrict__ o3,
    void* __restrict__ o4) {
  constexpr int K = 2048;
  constexpr int BK = 64;
  constexpr int NBUFA = (EPI == 1) ? 2 : 1;
  constexpr int WN = (NW == 8) ? 4 : 2;   // waves along N
  constexpr int WM = NW / WN;             // 2
  constexpr int MI = (128 / WM) / 16;     // 4
  constexpr int NI = (128 / WN) / 16;     // 4 (NW=4) or 2 (NW=8)
  __shared__ unsigned short sA[NBUFA][128 * BK];
  __shared__ unsigned short sB[128 * BK];
  const int tid = threadIdx.x;
  const int wave = tid >> 6, lane = tid & 63;
  const int l16 = lane & 15, lq = lane >> 4;
  const int wr = wave / WN, wc = wave % WN;
  const int m0 = blockIdx.y * 128, n0 = blockIdx.x * 128;
  const bool two = (EPI == 1) && (n0 < 4096);   // block-uniform

  f32x4 acc[MI][NI] = {};

  for (int k0 = 0; k0 < K; k0 += BK) {
    // stage: 1024 chunks of 8 bf16 per tile (128 rows x 8 chunks)
#pragma unroll
    for (int i = 0; i < 1024 / (NW * 64); ++i) {
      int c = i * (NW * 64) + tid;
      int row = c >> 3, cc = c & 7;
      int gcol = ((cc ^ (row & 7)) << 3);
      size_t ga = (size_t)(m0 + row) * K + k0 + gcol;
      size_t gb = (size_t)(n0 + row) * K + k0 + gcol;
      async_cp16(Ah + ga, sA[0] + c * 8);
      async_cp16(Bh + gb, sB + c * 8);
      if constexpr (EPI == 1) {
        if (two) async_cp16(Al + ga, sA[1] + c * 8);
      }
    }
    __syncthreads();

#pragma unroll
    for (int kk = 0; kk < 2; ++kk) {
      const int ci = (kk << 2) + lq;
      bf16x8 ah[MI], al[MI], bh[NI];
#pragma unroll
      for (int mi = 0; mi < MI; ++mi) {
        int row = wr * (MI * 16) + mi * 16 + l16;
        int off = row * BK + ((ci ^ (row & 7)) << 3);
        ah[mi] = *(const bf16x8*)(sA[0] + off);
        if constexpr (EPI == 1) {
          if (two) al[mi] = *(const bf16x8*)(sA[1] + off);
        }
      }
#pragma unroll
      for (int ni = 0; ni < NI; ++ni) {
        int row = wc * (NI * 16) + ni * 16 + l16;
        int off = row * BK + ((ci ^ (row & 7)) << 3);
        bh[ni] = *(const bf16x8*)(sB + off);
      }
#pragma unroll
      for (int mi = 0; mi < MI; ++mi)
#pragma unroll
        for (int ni = 0; ni < NI; ++ni) {
          acc[mi][ni] = MFMA16(ah[mi], bh[ni], acc[mi][ni]);
          if constexpr (EPI == 1) {
            if (two) acc[mi][ni] = MFMA16(al[mi], bh[ni], acc[mi][ni]);
          }
        }
    }
    __syncthreads();
  }

  // epilogue: C/D layout col=lane&15, row=(lane>>4)*4+reg (m89-verified)
#pragma unroll
  for (int mi = 0; mi < MI; ++mi) {
#pragma unroll
    for (int ni = 0; ni < NI; ++ni) {
      int row = m0 + wr * (MI * 16) + mi * 16 + lq * 4;
      int col = n0 + wc * (NI * 16) + ni * 16 + l16;
      float bv = bias[col];
      if constexpr (EPI == 0) {
        float* C = (float*)o0;
#pragma unroll
        for (int r = 0; r < 4; ++r)
          C[(size_t)(row + r) * 2048 + col] = acc[mi][ni][r] + bv;
      } else {
        if (col < 4096) {
          unsigned short* dh; unsigned short* dl; int cc;
          if (col < 2048) { dh = (unsigned short*)o0; dl = (unsigned short*)o1; cc = col; }
          else            { dh = (unsigned short*)o2; dl = (unsigned short*)o3; cc = col - 2048; }
#pragma unroll
          for (int r = 0; r < 4; ++r) {
            float v = acc[mi][ni][r] + bv;
            unsigned short h = f2b(v);
            unsigned short l = f2b(v - b2f(h));
            dh[(size_t)(row + r) * 2048 + cc] = h;
            dl[(size_t)(row + r) * 2048 + cc] = l;
          }
        } else {  // V^T [h*128+d][s]: 4 consecutive s per lane
          unsigned short* vt = (unsigned short*)o4;
          unsigned short hs[4];
#pragma unroll
          for (int r = 0; r < 4; ++r) hs[r] = f2b(acc[mi][ni][r] + bv);
          *(ushort4*)(vt + (size_t)(col - 4096) * 2048 + row) = make_ushort4(hs[0], hs[1], hs[2], hs[3]);
        }
      }
    }
  }
}

// ---------- flash attention (causal, no 1/sqrt(d) scaling — faithful to reference) ----------
// BQ=64 (4 waves x 16 rows), K-tiles of 64, d=128.
// Swapped-operand scheme: S^T = MFMA(K,Q); q-row = lane&15 -> softmax local + 2 shfl_xor.
// 2-term logits: S = Kh·(Qh+Ql)  [K-lo term dropped; validated r9: absmax 0.047]
__global__ __launch_bounds__(256, 2) void attn_fwd(
    const unsigned short* __restrict__ Qh, const unsigned short* __restrict__ Ql,
    const unsigned short* __restrict__ Kh,
    const unsigned short* __restrict__ Vt, unsigned short* __restrict__ aout) {
  const int head = blockIdx.y;
  const int x = blockIdx.x;                       // 0..31
  // balance CUs: co-resident blocks (b, b+256) differ only in head by 8 -> opposite qt length
  const int qt = (head < 8) ? x : (31 - x);
  const int tid = threadIdx.x;
  const int wave = tid >> 6, lane = tid & 63;
  const int l16 = lane & 15, lq = lane >> 4;

  __shared__ unsigned short sKh[64 * 128];
  __shared__ unsigned short sV[128 * 64];         // [d][kseq]
  __shared__ unsigned short sP[4][16 * 72];       // per-wave P tile [q][k], stride 72

  const int q0 = qt * 64 + wave * 16;

  // hoist Q fragments (rows q0+l16, d chunks of 8) — used as MFMA B-operand
  bf16x8 qh[4], ql[4];
#pragma unroll
  for (int kc = 0; kc < 4; ++kc) {
    size_t off = (size_t)(q0 + l16) * 2048 + head * 128 + kc * 32 + lq * 8;
    qh[kc] = *(const bf16x8*)(Qh + off);
    ql[kc] = *(const bf16x8*)(Ql + off);
  }

  f32x4 o[8] = {};                 // O^T: [d = nd*16 + lq*4 + r][q = l16]
  float mst = -1e30f, lst = 0.f;   // online-softmax state for q = l16 (replicated over lq)

  const int ktmax = qt + 1;
  for (int kt = 0; kt < ktmax; ++kt) {
    // stage K hi [64][128] and V^T [128][64], 8-chunk XOR swizzle per row
#pragma unroll
    for (int i = 0; i < 4; ++i) {
      int c = i * 256 + tid;
      {
        int row = c >> 4, cc = c & 15;
        int gc = ((cc ^ (row & 7)) << 3);
        size_t g = (size_t)(kt * 64 + row) * 2048 + head * 128 + gc;
        async_cp16(Kh + g, sKh + c * 8);
      }
      {
        int row = c >> 3, cc = c & 7;
        int gc = ((cc ^ (row & 7)) << 3);
        size_t g = (size_t)(head * 128 + row) * 2048 + kt * 64 + gc;
        async_cp16(Vt + g, sV + c * 8);
      }
    }
    __syncthreads();

    // S^T[64 k][16 q] in 4 reg-tiles: s[nk] rows k = kt*64 + nk*16 + lq*4 + r, col q = l16
    f32x4 s[4] = {};
    __builtin_amdgcn_s_setprio(1);
#pragma unroll
    for (int kc = 0; kc < 4; ++kc) {
#pragma unroll
      for (int nk = 0; nk < 4; ++nk) {
        int krow = nk * 16 + l16;
        int off = krow * 128 + ((((kc << 2) + lq) ^ (krow & 7)) << 3);
        bf16x8 kbh = *(const bf16x8*)(sKh + off);
        s[nk] = MFMA16(kbh, qh[kc], s[nk]);   // Kh·Qh^T
        s[nk] = MFMA16(kbh, ql[kc], s[nk]);   // Kh·Ql^T
      }
    }
    __builtin_amdgcn_s_setprio(0);

    // causal mask + online softmax — all 16 scores in this lane belong to q = q0 + l16
    const int qg = q0 + l16;
    float pv[16];
    float mx = -1e30f;
#pragma unroll
    for (int nk = 0; nk < 4; ++nk)
#pragma unroll
      for (int r = 0; r < 4; ++r) {
        int kg = kt * 64 + nk * 16 + lq * 4 + r;
        float v = s[nk][r];
        if (kg > qg) v = -1e30f;
        pv[nk * 4 + r] = v;
        mx = fmaxf(mx, v);
      }
    mx = fmaxf(mx, __shfl_xor(mx, 16));
    mx = fmaxf(mx, __shfl_xor(mx, 32));
    float mnew = fmaxf(mst, mx);
    float scale = __expf(mst - mnew);
    float rsum = 0.f;
#pragma unroll
    for (int nk = 0; nk < 4; ++nk) {
      unsigned short pb[4];
#pragma unroll
      for (int r = 0; r < 4; ++r) {
        pb[r] = f2b(__expf(pv[nk * 4 + r] - mnew));
        rsum += b2f(pb[r]);
      }
      // P[q = l16][k = nk*16 + lq*4 .. +3], aligned 8B write, wave-private
      *(ushort4*)(&sP[wave][l16 * 72 + nk * 16 + lq * 4]) = make_ushort4(pb[0], pb[1], pb[2], pb[3]);
    }
    rsum += __shfl_xor(rsum, 16);
    rsum += __shfl_xor(rsum, 32);
    lst = lst * scale + rsum;
    mst = mnew;
#pragma unroll
    for (int nd = 0; nd < 8; ++nd) {
      o[nd][0] *= scale; o[nd][1] *= scale; o[nd][2] *= scale; o[nd][3] *= scale;
    }

    // O^T += V^T·P^T : A = V^T d-rows (from sV), B = P q-rows (from sP)
    __builtin_amdgcn_s_setprio(1);
#pragma unroll
    for (int kc2 = 0; kc2 < 2; ++kc2) {
      bf16x8 pb = *(const bf16x8*)(&sP[wave][l16 * 72 + kc2 * 32 + lq * 8]);
#pragma unroll
      for (int nd = 0; nd < 8; ++nd) {
        int vrow = nd * 16 + l16;
        int off = vrow * 64 + ((((kc2 << 2) + lq) ^ (vrow & 7)) << 3);
        bf16x8 vb = *(const bf16x8*)(sV + off);
        o[nd] = MFMA16(vb, pb, o[nd]);
      }
    }
    __builtin_amdgcn_s_setprio(0);
    __syncthreads();
  }

  const float norm = 1.f / lst;
#pragma unroll
  for (int nd = 0; nd < 8; ++nd) {
    unsigned short hs[4];
#pragma unroll
    for (int r = 0; r < 4; ++r) hs[r] = f2b(o[nd][r] * norm);
    *(ushort4*)(aout + (size_t)(q0 + l16) * 2048 + head * 128 + nd * 16 + lq * 4) =
        make_ushort4(hs[0], hs[1], hs[2], hs[3]);
  }
}

// ---------- launch ----------
extern "C" void kernel_launch(void* const* d_in, const int* in_sizes, int n_in,
                              void* d_out, int out_size, void* d_ws, size_t ws_size,
                              hipStream_t stream) {
  const float* x    = (const float*)d_in[0];
  const float* Wqkv = (const float*)d_in[1];
  const float* bqkv = (const float*)d_in[2];
  const float* Wout = (const float*)d_in[3];
  const float* bout = (const float*)d_in[4];
  float* out = (float*)d_out;

  unsigned short* w = (unsigned short*)d_ws;
  const size_t SZ = (size_t)2048 * 2048;
  unsigned short* xh  = w;  w += SZ;
  unsigned short* xl  = w;  w += SZ;
  unsigned short* wqh = w;  w += (size_t)6144 * 2048;
  unsigned short* wo  = w;  w += SZ;
  unsigned short* qh  = w;  w += SZ;
  unsigned short* ql  = w;  w += SZ;
  unsigned short* kh  = w;  w += SZ;
  unsigned short* kl  = w;  w += SZ;
  unsigned short* vt  = w;  w += SZ;
  unsigned short* ao  = w;  w += SZ;
  (void)ws_size; (void)in_sizes; (void)n_in; (void)out_size; (void)kl;

  preprocess<<<8192, 256, 0, stream>>>(x, xh, xl, Wqkv, wqh, Wout, wo);
  // fused QKV projection: Q,K columns 2-term (xh+xl)@Wh; V columns 1-term into V^T layout
  gemm_bf16<4, 1><<<dim3(48, 16), 256, 0, stream>>>(xh, xl, wqh, bqkv,
                                                    qh, ql, kh, kl, vt);
  attn_fwd<<<dim3(32, 16), 256, 0, stream>>>(qh, ql, kh, vt, ao);
  gemm_bf16<8, 0><<<dim3(16, 16), 512, 0, stream>>>(ao, nullptr, wo, bout, out,
                                                    nullptr, nullptr, nullptr, nullptr);
}